// Round 3
// baseline (317.834 us; speedup 1.0000x reference)
//
#include <hip/hip_runtime.h>
#include <hip/hip_bf16.h>

// fp32 problem: b=2, s=2048, D=2048, 32 q-heads / 8 kv-groups, d=64
#define TOKENS   4096
#define SEQ      2048
#define DMODEL   2048
#define CONCAT   3072
#define NHEADS   32
#define NGROUPS  8
#define HPERG    4
#define CQ       2048
#define CK       512

typedef __attribute__((ext_vector_type(8))) short bf16x8;
typedef __attribute__((ext_vector_type(4))) float f32x4;

__device__ __forceinline__ ushort f2bf(float f) {
    __hip_bfloat16 h = __float2bfloat16(f);
    return __builtin_bit_cast(ushort, h);
}

#define GLOBAL_TO_LDS16(g, l)                                                  \
    __builtin_amdgcn_global_load_lds(                                          \
        (const __attribute__((address_space(1))) void*)(g),                    \
        (__attribute__((address_space(3))) void*)(l), 16, 0, 0)

// ---------------- RMSNorm: one block (256 thr) per token, bf16 out -------
__global__ void rmsnorm_kernel(const float* __restrict__ x,
                               const float* __restrict__ w,
                               ushort* __restrict__ y_bf) {
    int t = blockIdx.x;
    const float4* xr = (const float4*)(x + (size_t)t * DMODEL);
    float4 v[2];
    float ss = 0.f;
#pragma unroll
    for (int i = 0; i < 2; i++) {
        v[i] = xr[threadIdx.x + i * 256];
        ss += v[i].x * v[i].x + v[i].y * v[i].y + v[i].z * v[i].z + v[i].w * v[i].w;
    }
#pragma unroll
    for (int off = 32; off >= 1; off >>= 1) ss += __shfl_xor(ss, off);
    __shared__ float red[4];
    int wid = threadIdx.x >> 6;
    if ((threadIdx.x & 63) == 0) red[wid] = ss;
    __syncthreads();
    float total = red[0] + red[1] + red[2] + red[3];
    float scale = rsqrtf(total * (1.0f / DMODEL) + 1e-6f);
    const float4* wr = (const float4*)w;
    ushort4* yr = (ushort4*)(y_bf + (size_t)t * DMODEL);
#pragma unroll
    for (int i = 0; i < 2; i++) {
        int c = threadIdx.x + i * 256;
        float4 wv = wr[c];
        ushort4 o;
        o.x = f2bf(v[i].x * scale * wv.x);
        o.y = f2bf(v[i].y * scale * wv.y);
        o.z = f2bf(v[i].z * scale * wv.z);
        o.w = f2bf(v[i].w * scale * wv.w);
        yr[c] = o;
    }
}

// ---------------- fp32 -> bf16 cast (weights) ----------------------------
__global__ void pack_bf16_kernel(const float* __restrict__ src,
                                 ushort* __restrict__ dst, int n4) {
    int i = blockIdx.x * 256 + threadIdx.x;
    if (i < n4) {
        float4 v = ((const float4*)src)[i];
        ushort4 o;
        o.x = f2bf(v.x); o.y = f2bf(v.y); o.z = f2bf(v.z); o.w = f2bf(v.w);
        ((ushort4*)dst)[i] = o;
    }
}

// ---------------- 256xBN 8-phase MFMA GEMM -------------------------------
// C[M,N] = A[M,K] * B[N,K]^T, bf16 in / f32 out.  BN = 128*NFRAG.
// 512 thr = 8 waves (2M x 4N); wave tile 128 x (32*NFRAG); BK=64.
// Rolling half-tile buffer: halves in consumption order
//   half(4t+0)=A0(t) rows {wm*128+[0,64)}            (read P1)
//   half(4t+1)=B0(t) cols {wn*32N+[0,16N)}           (read P1)
//   half(4t+2)=B1(t) cols {wn*32N+[16N,32N)}         (read P2)
//   half(4t+3)=A1(t) rows {wm*128+[64,128)}          (read P3)
// Phase p=4t+j issues half p+7 (prologue pre-issues halves 0..6).
// Counted vmcnt per K-tile = loads of {A0,B0,B1} of over-next tile:
//   NFRAG=2: 2+2+2=6;  NFRAG=1: 2+1+1=4.  vmcnt(0) only entering last tile.
// LDS swizzle: linear dest + pre-swizzled global src; k-block stored at
// blk ^ (row&7) -> conflict-free ds_read_b128 frags.
#define LGKM(nn) asm volatile("s_waitcnt lgkmcnt(" #nn ")" ::: "memory")
#define VMC(nn)  asm volatile("s_waitcnt vmcnt(" #nn ")" ::: "memory")
#define SBAR()   __builtin_amdgcn_s_barrier()
#define SCHED0() __builtin_amdgcn_sched_barrier(0)
#define PRIO(p)  __builtin_amdgcn_s_setprio(p)

#define RD_A(mh)                                                              \
    _Pragma("unroll") for (int mi = 0; mi < 4; mi++)                          \
    _Pragma("unroll") for (int ks = 0; ks < 2; ks++)                          \
        af[mi][ks] = *(const bf16x8*)(Ab +                                    \
            ((arow0 + (mh) * 64 + mi * 16) * 8 +                              \
             ((ks * 4 + quad) ^ an)) * 8);

#define RD_B(nh)                                                              \
    _Pragma("unroll") for (int ni = 0; ni < NFRAG; ni++)                      \
    _Pragma("unroll") for (int ks = 0; ks < 2; ks++)                          \
        bfr[nh][ni][ks] = *(const bf16x8*)(Bb +                               \
            ((brow0 + (nh) * (16 * NFRAG) + ni * 16) * 8 +                    \
             ((ks * 4 + quad) ^ an)) * 8);

#define MMQ(mh, nh)                                                           \
    _Pragma("unroll") for (int mi = 0; mi < 4; mi++)                          \
    _Pragma("unroll") for (int ni = 0; ni < NFRAG; ni++)                      \
    _Pragma("unroll") for (int ks = 0; ks < 2; ks++)                          \
        acc[(mh) * 4 + mi][(nh) * NFRAG + ni] =                               \
            __builtin_amdgcn_mfma_f32_16x16x32_bf16(af[mi][ks],               \
                bfr[nh][ni][ks], acc[(mh) * 4 + mi][(nh) * NFRAG + ni],       \
                0, 0, 0);

#define ISSUE_HALF(H_)                                                        \
    {                                                                         \
        int H = (H_);                                                         \
        if (H < 4 * NT) {                                                     \
            int t2 = H >> 2, j2 = H & 3;                                      \
            int k0 = t2 << 6;                                                 \
            if (j2 == 0 || j2 == 3) {                                         \
                int half = (j2 == 3);                                         \
                ushort* lb = (ushort*)&As[t2 & 1][0];                         \
                _Pragma("unroll") for (int c = 0; c < 2; c++) {               \
                    int s = w * 2 + c;                                        \
                    int row = (s >> 3) * 128 + half * 64 + (s & 7) * 8;       \
                    const ushort* g = Aptr +                                  \
                        (size_t)(bm + row + l8) * K + k0 + kb8;               \
                    GLOBAL_TO_LDS16(g, lb + row * 64);                        \
                }                                                             \
            } else {                                                          \
                int half = (j2 == 2);                                         \
                ushort* lb = (ushort*)&Bs[t2 & 1][0];                         \
                if constexpr (NFRAG == 2) {                                   \
                    _Pragma("unroll") for (int c = 0; c < 2; c++) {           \
                        int s = w * 2 + c;                                    \
                        int row = (s >> 2) * 64 + half * 32 + (s & 3) * 8;    \
                        const ushort* g = Bptr +                              \
                            (size_t)(bn + row + l8) * K + k0 + kb8;           \
                        GLOBAL_TO_LDS16(g, lb + row * 64);                    \
                    }                                                         \
                } else {                                                      \
                    int row = (w >> 1) * 32 + half * 16 + (w & 1) * 8;        \
                    const ushort* g = Bptr +                                  \
                        (size_t)(bn + row + l8) * K + k0 + kb8;               \
                    GLOBAL_TO_LDS16(g, lb + row * 64);                        \
                }                                                             \
            }                                                                 \
        }                                                                     \
    }

#define VMC_STEADY()                                                          \
    { if constexpr (NFRAG == 2) { VMC(6); } else { VMC(4); } }

#define TILE(t_, BUF)                                                         \
    {                                                                         \
        const ushort* Ab = &As[BUF][0];                                       \
        const ushort* Bb = &Bs[BUF][0];                                       \
        /* phase 1: A0,B0 -> Q(0,0) */                                        \
        RD_A(0); RD_B(0);                                                     \
        ISSUE_HALF(4 * (t_) + 7);                                             \
        LGKM(8);                                                              \
        SBAR(); LGKM(0); SCHED0();                                            \
        PRIO(1); MMQ(0, 0); PRIO(0);                                          \
        SBAR();                                                               \
        /* phase 2: B1 -> Q(0,1) */                                           \
        RD_B(1);                                                              \
        ISSUE_HALF(4 * (t_) + 8);                                             \
        SBAR(); LGKM(0); SCHED0();                                            \
        PRIO(1); MMQ(0, 1); PRIO(0);                                          \
        SBAR();                                                               \
        /* phase 3: A1 -> Q(1,0) */                                           \
        RD_A(1);                                                              \
        ISSUE_HALF(4 * (t_) + 9);                                             \
        SBAR(); LGKM(0); SCHED0();                                            \
        PRIO(1); MMQ(1, 0); PRIO(0);                                          \
        SBAR();                                                               \
        /* phase 4: Q(1,1) + tile-boundary counted vmcnt */                   \
        ISSUE_HALF(4 * (t_) + 10);                                            \
        SBAR(); SCHED0();                                                     \
        PRIO(1); MMQ(1, 1); PRIO(0);                                          \
        if ((t_) + 2 < NT)        { VMC_STEADY(); }                           \
        else if ((t_) + 2 == NT)  { VMC(0); }                                 \
        SBAR();                                                               \
    }

template <bool EPILOGUE, int NFRAG>
__global__ __launch_bounds__(512, 2) void gemm_nt_8ph(
        const ushort* __restrict__ Aptr, const ushort* __restrict__ Bptr,
        float* __restrict__ C, const float* __restrict__ X,
        float* __restrict__ OUT, int M, int N, int K) {
    __shared__ __align__(16) ushort As[2][256 * 64];
    __shared__ __align__(16) ushort Bs[2][NFRAG * 128 * 64];

    const int bm = blockIdx.y * 256, bn = blockIdx.x * (128 * NFRAG);
    const int w = threadIdx.x >> 6, lane = threadIdx.x & 63;
    const int n = lane & 15, quad = lane >> 4;
    const int wm = w >> 2, wn = w & 3;
    const int an = n & 7;
    const int l8 = lane >> 3;
    const int kb8 = ((lane & 7) ^ l8) * 8;
    const int arow0 = wm * 128 + n;
    const int brow0 = wn * (32 * NFRAG) + n;
    const int NT = K >> 6;

    f32x4 acc[8][2 * NFRAG] = {};
    bf16x8 af[4][2], bfr[2][NFRAG][2];

    // prologue: pre-issue 7 halves (queue order), land first 4, barrier
    ISSUE_HALF(0); ISSUE_HALF(1); ISSUE_HALF(2); ISSUE_HALF(3);
    ISSUE_HALF(4); ISSUE_HALF(5); ISSUE_HALF(6);
    VMC_STEADY();
    SBAR();

    for (int tt = 0; tt < NT; tt += 2) {
        TILE(tt, 0);
        TILE(tt + 1, 1);
    }

#pragma unroll
    for (int mi = 0; mi < 8; mi++)
#pragma unroll
        for (int ni = 0; ni < 2 * NFRAG; ni++) {
            int row = bm + wm * 128 + mi * 16 + quad * 4;
            int col = bn + wn * (32 * NFRAG) + ni * 16 + n;
#pragma unroll
            for (int r = 0; r < 4; r++) {
                size_t idx = (size_t)(row + r) * N + col;
                float v = acc[mi][ni][r];
                if (EPILOGUE) OUT[idx] = X[idx] + v;
                else          C[idx]   = v;
            }
        }
}

// ------------- pack_qk: fused RoPE + bf16 cast + per-head layout ---------
// Q additionally pre-scaled by 0.125*log2(e) so QK^T MFMA output is the
// log2-domain score directly (no-max exp2 softmax in attention).
__global__ void pack_qk_kernel(const float* __restrict__ qkv,
                               __hip_bfloat16* __restrict__ Qb,
                               __hip_bfloat16* __restrict__ Kb) {
    int t = blockIdx.x;
    int b = t >> 11, s = t & (SEQ - 1);
    const float* row = qkv + (size_t)t * CONCAT;
    const float LOG2_THETA = 13.287712379549449f;
    const float QSCALE = 0.18033688011112042f;  // 0.125 * log2(e)
    for (int i = threadIdx.x; i < CQ + CK; i += 256) {
        int head, d;
        const float* hb;
        if (i < CQ) { head = i >> 6; d = i & 63; hb = row + head * 64; }
        else { head = (i - CQ) >> 6; d = (i - CQ) & 63; hb = row + CQ + head * 64; }
        int j = d & 31;
        float inv = exp2f(-((float)j / 32.0f) * LOG2_THETA);
        float ang = (float)s * inv;
        float c = cosf(ang), sn = sinf(ang);
        float val;
        if (d < 32) val = hb[d] * c - hb[d + 32] * sn;
        else        val = hb[d] * c + hb[d - 32] * sn;
        if (i < CQ) val *= QSCALE;
        __hip_bfloat16 bv = __float2bfloat16(val);
        if (i < CQ) {
            int g = head >> 2, h = head & 3;
            Qb[((size_t)((b * 8 + g) * 4 + h) * SEQ + s) * 64 + d] = bv;
        } else {
            Kb[((size_t)(b * 8 + head) * SEQ + s) * 64 + d] = bv;
        }
    }
}

// ------------- pack_v: transpose V to [b][g][d][s] bf16 via LDS ----------
__global__ void pack_v_kernel(const float* __restrict__ qkv,
                              __hip_bfloat16* __restrict__ Vb) {
    int st = blockIdx.x & 31, bg = blockIdx.x >> 5;
    int b = bg >> 3, g = bg & 7;
    __shared__ float tile[64][65];
    int tid = threadIdx.x;
    int ls = tid >> 6;
    int d = tid & 63;
#pragma unroll
    for (int i = 0; i < 16; i++) {
        int s = st * 64 + i * 4 + ls;
        tile[i * 4 + ls][d] = qkv[(size_t)(b * SEQ + s) * CONCAT + CQ + CK + g * 64 + d];
    }
    __syncthreads();
#pragma unroll
    for (int i = 0; i < 16; i++) {
        int drow = i * 4 + ls;
        int scol = tid & 63;
        Vb[((size_t)(bg * 64 + drow)) * SEQ + st * 64 + scol] =
            __float2bfloat16(tile[scol][drow]);
    }
}

// ---------------- MFMA flash attention, v3 -------------------------------
// Block = (b,g,h, 128-query tile); 4 waves x 32 query rows (2 groups of 16).
// No-max exp2 softmax (Q pre-scaled): p = v_exp(S2), l = ones-column MFMA.
// S^T via operand swap -> consecutive keys in-lane -> packed-dword P writes.
// v3: K/V staged by direct global_load_lds (no VGPR roundtrip, no ds_write),
// double-buffered with counted vmcnt(4) so next tile's loads fly under this
// tile's compute.  LDS layout = linear gload_lds dest; conflict-free reads
// via XOR on the GLOBAL source (both-sides-or-neither pattern):
//   K slot q (16B units) holds (key=q>>3, dblk=(q&7)^(key&7))
//     -> read group (key,dblk) at slot key*8 + (dblk^(key&7))
//   V slot q holds (d=q>>3, kb=(q&7)^(d&7))
//     -> read group (kb,d)   at slot d*8 + (kb^(d&7))
// P in per-wave LDS: dwords ((key>>3)*33 + q)*4 + ((key&7)>>1).
#define AISSUE(kt_, buf_)                                                     \
    {                                                                         \
        const ushort* Kg_ = Kg0 + (kt_) * 64 * 64;                            \
        const ushort* Vg_ = Vg0 + (kt_) * 64;                                 \
        _Pragma("unroll") for (int r_ = 0; r_ < 2; r_++) {                    \
            GLOBAL_TO_LDS16(Kg_ + (r_ * 32 + w * 8) * 64 + koff,              \
                            &Kl[buf_][(r_ * 256 + w * 64) * 8]);              \
            GLOBAL_TO_LDS16(Vg_ + (size_t)(r_ * 32 + w * 8) * SEQ + voff,     \
                            &Vl[buf_][(r_ * 256 + w * 64) * 8]);              \
        }                                                                     \
    }

__global__ __launch_bounds__(256) void attn_mfma_kernel(
        const ushort* __restrict__ Qb, const ushort* __restrict__ Kb,
        const ushort* __restrict__ Vb, ushort* __restrict__ o_bf) {
    __shared__ __align__(16) ushort Kl[2][512 * 8];
    __shared__ __align__(16) ushort Vl[2][512 * 8];
    __shared__ __align__(16) uint   Pl[4][1056];

    int blk = blockIdx.x;
    int qt  = 15 - (blk >> 6);          // longest blocks dispatch first
    int bgh = blk & 63;
    int h = bgh & 3, g = (bgh >> 2) & 7, b = bgh >> 5;
    int w = threadIdx.x >> 6, lane = threadIdx.x & 63;
    int n = lane & 15, quad = lane >> 4;
    const int an = n & 7;
    int Q0 = qt * 128;
    int qw = Q0 + w * 32;               // wave's first query row

    // staging lane constants: l3 = lane>>3 (row-in-8), lx = XOR'd 16B column
    const int l3 = lane >> 3;
    const int lx = (lane & 7) ^ l3;
    const int koff = l3 * 64 + lx * 8;  // ushort units into K tile row-major
    const int voff = l3 * SEQ + lx * 8; // ushort units into V [d][s]

    const ushort* Qh  = Qb + (size_t)((b * 8 + g) * 4 + h) * (SEQ * 64);
    const ushort* Kg0 = Kb + (size_t)(b * 8 + g) * (SEQ * 64);
    const ushort* Vg0 = Vb + (size_t)(b * 8 + g) * (64 * SEQ);

    // Q fragments (rows of Q; identical per-lane data for A- or B-operand use)
    bf16x8 aq[2][2];
#pragma unroll
    for (int qg = 0; qg < 2; qg++)
#pragma unroll
        for (int ks = 0; ks < 2; ks++)
            aq[qg][ks] = *(const bf16x8*)(
                Qh + (size_t)(qw + qg * 16 + n) * 64 + ks * 32 + quad * 8);

    f32x4 od[2][4] = {};
    f32x4 od4[2] = {};

    short onev = (n == 0) ? (short)0x3F80 : (short)0;
    bf16x8 bones = {onev, onev, onev, onev, onev, onev, onev, onev};

    uint* Pw = Pl[w];
    int nkt = qt * 2 + 2;

    // prologue: tiles 0 and 1 in flight (4 loads each per wave)
    AISSUE(0, 0);
    AISSUE(1, 1);

    for (int kt = 0; kt < nkt; kt++) {
        int buf = kt & 1;
        if (kt + 1 < nkt) { VMC(4); } else { VMC(0); }
        SBAR(); SCHED0();                // buf[kt&1] fully loaded, all waves

        bool act1 = (kt * 64 <= qw + 31);   // any of this wave's rows see kt?
        if (act1) {
            bool act0 = (kt * 64 <= qw + 15);
            const ushort* Kb_ = Kl[buf];
            const ushort* Vb_ = Vl[buf];

            // S^T = K Q^T (operand swap), exp2, pack, P write
#pragma unroll
            for (int t16k = 0; t16k < 4; t16k++) {
                int krow = (t16k * 16 + n) * 8;
                bf16x8 kf0 = *(const bf16x8*)(Kb_ + (krow + (quad ^ an)) * 8);
                bf16x8 kf1 = *(const bf16x8*)(Kb_ + (krow + ((quad + 4) ^ an)) * 8);
                int key0 = kt * 64 + t16k * 16 + quad * 4;
#pragma unroll
                for (int qg = 0; qg < 2; qg++) {
                    if (qg == 0 && !act0) continue;
                    f32x4 c = {};
                    c = __builtin_amdgcn_mfma_f32_16x16x32_bf16(kf0, aq[qg][0], c, 0, 0, 0);
                    c = __builtin_amdgcn_mfma_f32_16x16x32_bf16(kf1, aq[qg][1], c, 0, 0, 0);
                    int qrow = qw + qg * 16 + n;
                    float p[4];
                    if (kt * 64 + 63 > qw + qg * 16) {   // tile may mask
#pragma unroll
                        for (int r = 0; r < 4; r++)
                            p[r] = (key0 + r <= qrow) ? __builtin_amdgcn_exp2f(c[r]) : 0.f;
                    } else {
#pragma unroll
                        for (int r = 0; r < 4; r++)
                            p[r] = __builtin_amdgcn_exp2f(c[r]);
                    }
                    uint d0 = ((uint)f2bf(p[1]) << 16) | f2bf(p[0]);
                    uint d1 = ((uint)f2bf(p[3]) << 16) | f2bf(p[2]);
                    int base = ((t16k * 2 + (quad >> 1)) * 33 + qg * 16 + n) * 4
                               + (quad & 1) * 2;
                    Pw[base]     = d0;
                    Pw[base + 1] = d1;
                }
            }

            // O += P V   (+ ones column accumulates l)
#pragma unroll
            for (int kb2 = 0; kb2 < 2; kb2++) {
                int kb = kb2 * 4 + quad;
                bf16x8 bv[4];
#pragma unroll
                for (int dt = 0; dt < 4; dt++)
                    bv[dt] = *(const bf16x8*)(Vb_ +
                        (((dt * 16 + n) * 8 + (kb ^ an)) * 8));
#pragma unroll
                for (int qg = 0; qg < 2; qg++) {
                    if (qg == 0 && !act0) continue;
                    bf16x8 ap = *(const bf16x8*)(
                        (const ushort*)Pw + ((kb2 * 4 + quad) * 33 + qg * 16 + n) * 8);
#pragma unroll
                    for (int dt = 0; dt < 4; dt++)
                        od[qg][dt] = __builtin_amdgcn_mfma_f32_16x16x32_bf16(
                            ap, bv[dt], od[qg][dt], 0, 0, 0);
                    od4[qg] = __builtin_amdgcn_mfma_f32_16x16x32_bf16(
                        ap, bones, od4[qg], 0, 0, 0);
                }
            }
        }

        SCHED0(); SBAR();                // all reads of buf done
        if (kt + 2 < nkt) AISSUE(kt + 2, buf);
    }

    // epilogue: l lives in column 0 of od4 (lane n==0); broadcast, divide
#pragma unroll
    for (int qg = 0; qg < 2; qg++) {
        float linv[4];
#pragma unroll
        for (int r = 0; r < 4; r++) {
            float lv = __shfl(od4[qg][r], lane & 48);
            linv[r] = __builtin_amdgcn_rcpf(lv);
        }
#pragma unroll
        for (int dt = 0; dt < 4; dt++)
#pragma unroll
            for (int r = 0; r < 4; r++) {
                int q = qw + qg * 16 + quad * 4 + r;
                int col = (g * 4 + h) * 64 + dt * 16 + n;
                o_bf[(size_t)(b * SEQ + q) * DMODEL + col] =
                    f2bf(od[qg][dt][r] * linv[r]);
            }
    }
}

extern "C" void kernel_launch(void* const* d_in, const int* in_sizes, int n_in,
                              void* d_out, int out_size, void* d_ws, size_t ws_size,
                              hipStream_t stream) {
    const float* x     = (const float*)d_in[0];
    const float* w_in  = (const float*)d_in[1];
    const float* w_out = (const float*)d_in[2];
    const float* rms_w = (const float*)d_in[3];
    float* out = (float*)d_out;

    // Workspace layout with liveness overlap (peak 76 MB):
    //   [0,48)MB  qkv f32           -> after packs: o_bf [0,16), w_out_bf [16,24)
    //   [48,64)MB y_bf              -> after GEMM-in: Qb
    //   [64,76)MB w_in_bf           -> after GEMM-in: Kb [64,68), Vb [68,72)
    const size_t MB = 1024 * 1024;
    char* ws = (char*)d_ws;
    float*  qkv      = (float*)ws;
    ushort* y_bf     = (ushort*)(ws + 48 * MB);
    ushort* w_in_bf  = (ushort*)(ws + 64 * MB);
    ushort* Qb       = (ushort*)(ws + 48 * MB);
    ushort* Kb       = (ushort*)(ws + 64 * MB);
    ushort* Vb       = (ushort*)(ws + 68 * MB);
    ushort* o_bf     = (ushort*)ws;
    ushort* w_out_bf = (ushort*)(ws + 16 * MB);

    rmsnorm_kernel<<<TOKENS, 256, 0, stream>>>(x, rms_w, y_bf);
    pack_bf16_kernel<<<(CONCAT * DMODEL / 4 + 255) / 256, 256, 0, stream>>>(
        w_in, w_in_bf, CONCAT * DMODEL / 4);

    gemm_nt_8ph<false, 2><<<dim3(CONCAT / 256, TOKENS / 256), 512, 0, stream>>>(
        y_bf, w_in_bf, qkv, nullptr, nullptr, TOKENS, CONCAT, DMODEL);

    pack_qk_kernel<<<TOKENS, 256, 0, stream>>>(qkv, (__hip_bfloat16*)Qb,
                                               (__hip_bfloat16*)Kb);
    pack_v_kernel<<<512, 256, 0, stream>>>(qkv, (__hip_bfloat16*)Vb);
    pack_bf16_kernel<<<(DMODEL * DMODEL / 4 + 255) / 256, 256, 0, stream>>>(
        w_out, w_out_bf, DMODEL * DMODEL / 4);

    attn_mfma_kernel<<<1024, 256, 0, stream>>>(Qb, Kb, Vb, o_bf);

    gemm_nt_8ph<true, 1><<<dim3(DMODEL / 128, TOKENS / 256), 512, 0, stream>>>(
        o_bf, w_out_bf, nullptr, x, out, TOKENS, DMODEL, DMODEL);
}

// Round 4
// 300.882 us; speedup vs baseline: 1.0563x; 1.0563x over previous
//
#include <hip/hip_runtime.h>
#include <hip/hip_bf16.h>

// fp32 problem: b=2, s=2048, D=2048, 32 q-heads / 8 kv-groups, d=64
#define TOKENS   4096
#define SEQ      2048
#define DMODEL   2048
#define CONCAT   3072
#define NHEADS   32
#define NGROUPS  8
#define HPERG    4
#define CQ       2048
#define CK       512

typedef __attribute__((ext_vector_type(8))) short bf16x8;
typedef __attribute__((ext_vector_type(4))) float f32x4;

__device__ __forceinline__ ushort f2bf(float f) {
    __hip_bfloat16 h = __float2bfloat16(f);
    return __builtin_bit_cast(ushort, h);
}

#define GLOBAL_TO_LDS16(g, l)                                                  \
    __builtin_amdgcn_global_load_lds(                                          \
        (const __attribute__((address_space(1))) void*)(g),                    \
        (__attribute__((address_space(3))) void*)(l), 16, 0, 0)

// ---------------- RMSNorm: one block (256 thr) per token, bf16 out -------
__global__ void rmsnorm_kernel(const float* __restrict__ x,
                               const float* __restrict__ w,
                               ushort* __restrict__ y_bf) {
    int t = blockIdx.x;
    const float4* xr = (const float4*)(x + (size_t)t * DMODEL);
    float4 v[2];
    float ss = 0.f;
#pragma unroll
    for (int i = 0; i < 2; i++) {
        v[i] = xr[threadIdx.x + i * 256];
        ss += v[i].x * v[i].x + v[i].y * v[i].y + v[i].z * v[i].z + v[i].w * v[i].w;
    }
#pragma unroll
    for (int off = 32; off >= 1; off >>= 1) ss += __shfl_xor(ss, off);
    __shared__ float red[4];
    int wid = threadIdx.x >> 6;
    if ((threadIdx.x & 63) == 0) red[wid] = ss;
    __syncthreads();
    float total = red[0] + red[1] + red[2] + red[3];
    float scale = rsqrtf(total * (1.0f / DMODEL) + 1e-6f);
    const float4* wr = (const float4*)w;
    ushort4* yr = (ushort4*)(y_bf + (size_t)t * DMODEL);
#pragma unroll
    for (int i = 0; i < 2; i++) {
        int c = threadIdx.x + i * 256;
        float4 wv = wr[c];
        ushort4 o;
        o.x = f2bf(v[i].x * scale * wv.x);
        o.y = f2bf(v[i].y * scale * wv.y);
        o.z = f2bf(v[i].z * scale * wv.z);
        o.w = f2bf(v[i].w * scale * wv.w);
        yr[c] = o;
    }
}

// ---------------- fp32 -> bf16 cast (weights) ----------------------------
__global__ void pack_bf16_kernel(const float* __restrict__ src,
                                 ushort* __restrict__ dst, int n4) {
    int i = blockIdx.x * 256 + threadIdx.x;
    if (i < n4) {
        float4 v = ((const float4*)src)[i];
        ushort4 o;
        o.x = f2bf(v.x); o.y = f2bf(v.y); o.z = f2bf(v.z); o.w = f2bf(v.w);
        ((ushort4*)dst)[i] = o;
    }
}

// ---------------- 256xBN 8-phase MFMA GEMM -------------------------------
// C[M,N] = A[M,K] * B[N,K]^T, bf16 in / f32 out.  BN = 128*NFRAG.
// 512 thr = 8 waves (2M x 4N); wave tile 128 x (32*NFRAG); BK=64.
// Rolling half-tile buffer: halves in consumption order
//   half(4t+0)=A0(t) rows {wm*128+[0,64)}            (read P1)
//   half(4t+1)=B0(t) cols {wn*32N+[0,16N)}           (read P1)
//   half(4t+2)=B1(t) cols {wn*32N+[16N,32N)}         (read P2)
//   half(4t+3)=A1(t) rows {wm*128+[64,128)}          (read P3)
// Phase p=4t+j issues half p+7 (prologue pre-issues halves 0..6).
// Counted vmcnt per K-tile = loads of {A0,B0,B1} of over-next tile:
//   NFRAG=2: 2+2+2=6;  NFRAG=1: 2+1+1=4.  vmcnt(0) only entering last tile.
// LDS swizzle: linear dest + pre-swizzled global src; k-block stored at
// blk ^ (row&7) -> conflict-free ds_read_b128 frags.
// T1: XCD-aware block swizzle (nwg%8==0 for both call sites -> bijective).
#define LGKM(nn) asm volatile("s_waitcnt lgkmcnt(" #nn ")" ::: "memory")
#define VMC(nn)  asm volatile("s_waitcnt vmcnt(" #nn ")" ::: "memory")
#define SBAR()   __builtin_amdgcn_s_barrier()
#define SCHED0() __builtin_amdgcn_sched_barrier(0)
#define PRIO(p)  __builtin_amdgcn_s_setprio(p)

#define RD_A(mh)                                                              \
    _Pragma("unroll") for (int mi = 0; mi < 4; mi++)                          \
    _Pragma("unroll") for (int ks = 0; ks < 2; ks++)                          \
        af[mi][ks] = *(const bf16x8*)(Ab +                                    \
            ((arow0 + (mh) * 64 + mi * 16) * 8 +                              \
             ((ks * 4 + quad) ^ an)) * 8);

#define RD_B(nh)                                                              \
    _Pragma("unroll") for (int ni = 0; ni < NFRAG; ni++)                      \
    _Pragma("unroll") for (int ks = 0; ks < 2; ks++)                          \
        bfr[nh][ni][ks] = *(const bf16x8*)(Bb +                               \
            ((brow0 + (nh) * (16 * NFRAG) + ni * 16) * 8 +                    \
             ((ks * 4 + quad) ^ an)) * 8);

#define MMQ(mh, nh)                                                           \
    _Pragma("unroll") for (int mi = 0; mi < 4; mi++)                          \
    _Pragma("unroll") for (int ni = 0; ni < NFRAG; ni++)                      \
    _Pragma("unroll") for (int ks = 0; ks < 2; ks++)                          \
        acc[(mh) * 4 + mi][(nh) * NFRAG + ni] =                               \
            __builtin_amdgcn_mfma_f32_16x16x32_bf16(af[mi][ks],               \
                bfr[nh][ni][ks], acc[(mh) * 4 + mi][(nh) * NFRAG + ni],       \
                0, 0, 0);

#define ISSUE_HALF(H_)                                                        \
    {                                                                         \
        int H = (H_);                                                         \
        if (H < 4 * NT) {                                                     \
            int t2 = H >> 2, j2 = H & 3;                                      \
            int k0 = t2 << 6;                                                 \
            if (j2 == 0 || j2 == 3) {                                         \
                int half = (j2 == 3);                                         \
                ushort* lb = (ushort*)&As[t2 & 1][0];                         \
                _Pragma("unroll") for (int c = 0; c < 2; c++) {               \
                    int s = w * 2 + c;                                        \
                    int row = (s >> 3) * 128 + half * 64 + (s & 7) * 8;       \
                    const ushort* g = Aptr +                                  \
                        (size_t)(bm + row + l8) * K + k0 + kb8;               \
                    GLOBAL_TO_LDS16(g, lb + row * 64);                        \
                }                                                             \
            } else {                                                          \
                int half = (j2 == 2);                                         \
                ushort* lb = (ushort*)&Bs[t2 & 1][0];                         \
                if constexpr (NFRAG == 2) {                                   \
                    _Pragma("unroll") for (int c = 0; c < 2; c++) {           \
                        int s = w * 2 + c;                                    \
                        int row = (s >> 2) * 64 + half * 32 + (s & 3) * 8;    \
                        const ushort* g = Bptr +                              \
                            (size_t)(bn + row + l8) * K + k0 + kb8;           \
                        GLOBAL_TO_LDS16(g, lb + row * 64);                    \
                    }                                                         \
                } else {                                                      \
                    int row = (w >> 1) * 32 + half * 16 + (w & 1) * 8;        \
                    const ushort* g = Bptr +                                  \
                        (size_t)(bn + row + l8) * K + k0 + kb8;               \
                    GLOBAL_TO_LDS16(g, lb + row * 64);                        \
                }                                                             \
            }                                                                 \
        }                                                                     \
    }

#define VMC_STEADY()                                                          \
    { if constexpr (NFRAG == 2) { VMC(6); } else { VMC(4); } }

#define TILE(t_, BUF)                                                         \
    {                                                                         \
        const ushort* Ab = &As[BUF][0];                                       \
        const ushort* Bb = &Bs[BUF][0];                                       \
        /* phase 1: A0,B0 -> Q(0,0) */                                        \
        RD_A(0); RD_B(0);                                                     \
        ISSUE_HALF(4 * (t_) + 7);                                             \
        LGKM(8);                                                              \
        SBAR(); LGKM(0); SCHED0();                                            \
        PRIO(1); MMQ(0, 0); PRIO(0);                                          \
        SBAR();                                                               \
        /* phase 2: B1 -> Q(0,1) */                                           \
        RD_B(1);                                                              \
        ISSUE_HALF(4 * (t_) + 8);                                             \
        SBAR(); LGKM(0); SCHED0();                                            \
        PRIO(1); MMQ(0, 1); PRIO(0);                                          \
        SBAR();                                                               \
        /* phase 3: A1 -> Q(1,0) */                                           \
        RD_A(1);                                                              \
        ISSUE_HALF(4 * (t_) + 9);                                             \
        SBAR(); LGKM(0); SCHED0();                                            \
        PRIO(1); MMQ(1, 0); PRIO(0);                                          \
        SBAR();                                                               \
        /* phase 4: Q(1,1) + tile-boundary counted vmcnt */                   \
        ISSUE_HALF(4 * (t_) + 10);                                            \
        SBAR(); SCHED0();                                                     \
        PRIO(1); MMQ(1, 1); PRIO(0);                                          \
        if ((t_) + 2 < NT)        { VMC_STEADY(); }                           \
        else if ((t_) + 2 == NT)  { VMC(0); }                                 \
        SBAR();                                                               \
    }

template <bool EPILOGUE, int NFRAG>
__global__ __launch_bounds__(512, 2) void gemm_nt_8ph(
        const ushort* __restrict__ Aptr, const ushort* __restrict__ Bptr,
        float* __restrict__ C, const float* __restrict__ X,
        float* __restrict__ OUT, int M, int N, int K) {
    __shared__ __align__(16) ushort As[2][256 * 64];
    __shared__ __align__(16) ushort Bs[2][NFRAG * 128 * 64];

    // XCD-aware swizzle: XCD k owns a contiguous chunk of tile space.
    int nwg = (int)(gridDim.x * gridDim.y);
    int lin = (int)(blockIdx.y * gridDim.x + blockIdx.x);
    int swz = lin;
    if ((nwg & 7) == 0) swz = (lin & 7) * (nwg >> 3) + (lin >> 3);
    const int bm = (swz / (int)gridDim.x) * 256;
    const int bn = (swz % (int)gridDim.x) * (128 * NFRAG);

    const int w = threadIdx.x >> 6, lane = threadIdx.x & 63;
    const int n = lane & 15, quad = lane >> 4;
    const int wm = w >> 2, wn = w & 3;
    const int an = n & 7;
    const int l8 = lane >> 3;
    const int kb8 = ((lane & 7) ^ l8) * 8;
    const int arow0 = wm * 128 + n;
    const int brow0 = wn * (32 * NFRAG) + n;
    const int NT = K >> 6;

    f32x4 acc[8][2 * NFRAG] = {};
    bf16x8 af[4][2], bfr[2][NFRAG][2];

    // prologue: pre-issue 7 halves (queue order), land first 4, barrier
    ISSUE_HALF(0); ISSUE_HALF(1); ISSUE_HALF(2); ISSUE_HALF(3);
    ISSUE_HALF(4); ISSUE_HALF(5); ISSUE_HALF(6);
    VMC_STEADY();
    SBAR();

    for (int tt = 0; tt < NT; tt += 2) {
        TILE(tt, 0);
        TILE(tt + 1, 1);
    }

#pragma unroll
    for (int mi = 0; mi < 8; mi++)
#pragma unroll
        for (int ni = 0; ni < 2 * NFRAG; ni++) {
            int row = bm + wm * 128 + mi * 16 + quad * 4;
            int col = bn + wn * (32 * NFRAG) + ni * 16 + n;
#pragma unroll
            for (int r = 0; r < 4; r++) {
                size_t idx = (size_t)(row + r) * N + col;
                float v = acc[mi][ni][r];
                if (EPILOGUE) OUT[idx] = X[idx] + v;
                else          C[idx]   = v;
            }
        }
}

// ------------- pack_qkv: fused RoPE-pack (Q,K) + V transpose -------------
// Blocks [0,TOKENS): RoPE + bf16 cast + per-head layout for Q,K.
//   Trig via per-block LDS table: only 32 distinct (cos,sin) pairs per
//   token; 32 lanes compute them once, all elements read LDS (kills the
//   per-element libm sinf/cosf VALU cost).  Pair-processing (d, d+32)
//   reads each f32 exactly once.  Q pre-scaled by 0.125*log2(e) so QK^T
//   MFMA output is the log2-domain score (no-max exp2 softmax).
// Blocks [TOKENS, TOKENS+512): V transpose to [b][g][d][s] bf16 via LDS.
__global__ void pack_qkv_kernel(const float* __restrict__ qkv,
                                ushort* __restrict__ Qb,
                                ushort* __restrict__ Kb,
                                ushort* __restrict__ Vb) {
    __shared__ float cs[32], sn[32];
    __shared__ float tile[64][65];
    int tid = threadIdx.x;

    if (blockIdx.x < TOKENS) {
        int t = blockIdx.x;
        int b = t >> 11, s = t & (SEQ - 1);
        const float* row = qkv + (size_t)t * CONCAT;
        if (tid < 32) {
            const float LOG2_THETA = 13.287712379549449f;
            float inv = exp2f(-((float)tid / 32.0f) * LOG2_THETA);
            float ang = (float)s * inv;
            cs[tid] = cosf(ang);
            sn[tid] = sinf(ang);
        }
        __syncthreads();
        const float QSCALE = 0.18033688011112042f;  // 0.125 * log2(e)
#pragma unroll
        for (int it = 0; it < (CQ + CK) / 2 / 256; it++) {
            int p = tid + it * 256;
            int head = p >> 5, j = p & 31;
            const float* hb = row + head * 64;
            float x1 = hb[j], x2 = hb[j + 32];
            float c = cs[j], s2 = sn[j];
            float o1 = x1 * c - x2 * s2;
            float o2 = x2 * c + x1 * s2;
            if (head < 32) {
                o1 *= QSCALE; o2 *= QSCALE;
                int g = head >> 2, h = head & 3;
                ushort* q = Qb + ((size_t)((b * 8 + g) * 4 + h) * SEQ + s) * 64;
                q[j]      = f2bf(o1);
                q[j + 32] = f2bf(o2);
            } else {
                int kh = head - 32;
                ushort* kk = Kb + ((size_t)(b * 8 + kh) * SEQ + s) * 64;
                kk[j]      = f2bf(o1);
                kk[j + 32] = f2bf(o2);
            }
        }
    } else {
        int bid = blockIdx.x - TOKENS;
        int st = bid & 31, bg = bid >> 5;
        int b = bg >> 3, g = bg & 7;
        int ls = tid >> 6;
        int d = tid & 63;
#pragma unroll
        for (int i = 0; i < 16; i++) {
            int s = st * 64 + i * 4 + ls;
            tile[i * 4 + ls][d] =
                qkv[(size_t)(b * SEQ + s) * CONCAT + CQ + CK + g * 64 + d];
        }
        __syncthreads();
#pragma unroll
        for (int i = 0; i < 16; i++) {
            int drow = i * 4 + ls;
            int scol = tid & 63;
            Vb[((size_t)(bg * 64 + drow)) * SEQ + st * 64 + scol] =
                f2bf(tile[scol][drow]);
        }
    }
}

// ---------------- MFMA flash attention, v3 -------------------------------
// Block = (b,g,h, 128-query tile); 4 waves x 32 query rows (2 groups of 16).
// No-max exp2 softmax (Q pre-scaled): p = v_exp(S2), l = ones-column MFMA.
// S^T via operand swap -> consecutive keys in-lane -> packed-dword P writes.
// v3: K/V staged by direct global_load_lds (no VGPR roundtrip, no ds_write),
// double-buffered with counted vmcnt(4) so next tile's loads fly under this
// tile's compute.  LDS layout = linear gload_lds dest; conflict-free reads
// via XOR on the GLOBAL source (both-sides-or-neither pattern):
//   K slot q (16B units) holds (key=q>>3, dblk=(q&7)^(key&7))
//     -> read group (key,dblk) at slot key*8 + (dblk^(key&7))
//   V slot q holds (d=q>>3, kb=(q&7)^(d&7))
//     -> read group (kb,d)   at slot d*8 + (kb^(d&7))
// P in per-wave LDS: dwords ((key>>3)*33 + q)*4 + ((key&7)>>1).
#define AISSUE(kt_, buf_)                                                     \
    {                                                                         \
        const ushort* Kg_ = Kg0 + (kt_) * 64 * 64;                            \
        const ushort* Vg_ = Vg0 + (kt_) * 64;                                 \
        _Pragma("unroll") for (int r_ = 0; r_ < 2; r_++) {                    \
            GLOBAL_TO_LDS16(Kg_ + (r_ * 32 + w * 8) * 64 + koff,              \
                            &Kl[buf_][(r_ * 256 + w * 64) * 8]);              \
            GLOBAL_TO_LDS16(Vg_ + (size_t)(r_ * 32 + w * 8) * SEQ + voff,     \
                            &Vl[buf_][(r_ * 256 + w * 64) * 8]);              \
        }                                                                     \
    }

__global__ __launch_bounds__(256) void attn_mfma_kernel(
        const ushort* __restrict__ Qb, const ushort* __restrict__ Kb,
        const ushort* __restrict__ Vb, ushort* __restrict__ o_bf) {
    __shared__ __align__(16) ushort Kl[2][512 * 8];
    __shared__ __align__(16) ushort Vl[2][512 * 8];
    __shared__ __align__(16) uint   Pl[4][1056];

    int blk = blockIdx.x;
    int qt  = 15 - (blk >> 6);          // longest blocks dispatch first
    int bgh = blk & 63;
    int h = bgh & 3, g = (bgh >> 2) & 7, b = bgh >> 5;
    int w = threadIdx.x >> 6, lane = threadIdx.x & 63;
    int n = lane & 15, quad = lane >> 4;
    const int an = n & 7;
    int Q0 = qt * 128;
    int qw = Q0 + w * 32;               // wave's first query row

    // staging lane constants: l3 = lane>>3 (row-in-8), lx = XOR'd 16B column
    const int l3 = lane >> 3;
    const int lx = (lane & 7) ^ l3;
    const int koff = l3 * 64 + lx * 8;  // ushort units into K tile row-major
    const int voff = l3 * SEQ + lx * 8; // ushort units into V [d][s]

    const ushort* Qh  = Qb + (size_t)((b * 8 + g) * 4 + h) * (SEQ * 64);
    const ushort* Kg0 = Kb + (size_t)(b * 8 + g) * (SEQ * 64);
    const ushort* Vg0 = Vb + (size_t)(b * 8 + g) * (64 * SEQ);

    // Q fragments (rows of Q; identical per-lane data for A- or B-operand use)
    bf16x8 aq[2][2];
#pragma unroll
    for (int qg = 0; qg < 2; qg++)
#pragma unroll
        for (int ks = 0; ks < 2; ks++)
            aq[qg][ks] = *(const bf16x8*)(
                Qh + (size_t)(qw + qg * 16 + n) * 64 + ks * 32 + quad * 8);

    f32x4 od[2][4] = {};
    f32x4 od4[2] = {};

    short onev = (n == 0) ? (short)0x3F80 : (short)0;
    bf16x8 bones = {onev, onev, onev, onev, onev, onev, onev, onev};

    uint* Pw = Pl[w];
    int nkt = qt * 2 + 2;

    // prologue: tiles 0 and 1 in flight (4 loads each per wave)
    AISSUE(0, 0);
    AISSUE(1, 1);

    for (int kt = 0; kt < nkt; kt++) {
        int buf = kt & 1;
        if (kt + 1 < nkt) { VMC(4); } else { VMC(0); }
        SBAR(); SCHED0();                // buf[kt&1] fully loaded, all waves

        bool act1 = (kt * 64 <= qw + 31);   // any of this wave's rows see kt?
        if (act1) {
            bool act0 = (kt * 64 <= qw + 15);
            const ushort* Kb_ = Kl[buf];
            const ushort* Vb_ = Vl[buf];

            // S^T = K Q^T (operand swap), exp2, pack, P write
#pragma unroll
            for (int t16k = 0; t16k < 4; t16k++) {
                int krow = (t16k * 16 + n) * 8;
                bf16x8 kf0 = *(const bf16x8*)(Kb_ + (krow + (quad ^ an)) * 8);
                bf16x8 kf1 = *(const bf16x8*)(Kb_ + (krow + ((quad + 4) ^ an)) * 8);
                int key0 = kt * 64 + t16k * 16 + quad * 4;
#pragma unroll
                for (int qg = 0; qg < 2; qg++) {
                    if (qg == 0 && !act0) continue;
                    f32x4 c = {};
                    c = __builtin_amdgcn_mfma_f32_16x16x32_bf16(kf0, aq[qg][0], c, 0, 0, 0);
                    c = __builtin_amdgcn_mfma_f32_16x16x32_bf16(kf1, aq[qg][1], c, 0, 0, 0);
                    int qrow = qw + qg * 16 + n;
                    float p[4];
                    if (kt * 64 + 63 > qw + qg * 16) {   // tile may mask
#pragma unroll
                        for (int r = 0; r < 4; r++)
                            p[r] = (key0 + r <= qrow) ? __builtin_amdgcn_exp2f(c[r]) : 0.f;
                    } else {
#pragma unroll
                        for (int r = 0; r < 4; r++)
                            p[r] = __builtin_amdgcn_exp2f(c[r]);
                    }
                    uint d0 = ((uint)f2bf(p[1]) << 16) | f2bf(p[0]);
                    uint d1 = ((uint)f2bf(p[3]) << 16) | f2bf(p[2]);
                    int base = ((t16k * 2 + (quad >> 1)) * 33 + qg * 16 + n) * 4
                               + (quad & 1) * 2;
                    Pw[base]     = d0;
                    Pw[base + 1] = d1;
                }
            }

            // O += P V   (+ ones column accumulates l)
#pragma unroll
            for (int kb2 = 0; kb2 < 2; kb2++) {
                int kb = kb2 * 4 + quad;
                bf16x8 bv[4];
#pragma unroll
                for (int dt = 0; dt < 4; dt++)
                    bv[dt] = *(const bf16x8*)(Vb_ +
                        (((dt * 16 + n) * 8 + (kb ^ an)) * 8));
#pragma unroll
                for (int qg = 0; qg < 2; qg++) {
                    if (qg == 0 && !act0) continue;
                    bf16x8 ap = *(const bf16x8*)(
                        (const ushort*)Pw + ((kb2 * 4 + quad) * 33 + qg * 16 + n) * 8);
#pragma unroll
                    for (int dt = 0; dt < 4; dt++)
                        od[qg][dt] = __builtin_amdgcn_mfma_f32_16x16x32_bf16(
                            ap, bv[dt], od[qg][dt], 0, 0, 0);
                    od4[qg] = __builtin_amdgcn_mfma_f32_16x16x32_bf16(
                        ap, bones, od4[qg], 0, 0, 0);
                }
            }
        }

        SCHED0(); SBAR();                // all reads of buf done
        if (kt + 2 < nkt) AISSUE(kt + 2, buf);
    }

    // epilogue: l lives in column 0 of od4 (lane n==0); broadcast, divide
#pragma unroll
    for (int qg = 0; qg < 2; qg++) {
        float linv[4];
#pragma unroll
        for (int r = 0; r < 4; r++) {
            float lv = __shfl(od4[qg][r], lane & 48);
            linv[r] = __builtin_amdgcn_rcpf(lv);
        }
#pragma unroll
        for (int dt = 0; dt < 4; dt++)
#pragma unroll
            for (int r = 0; r < 4; r++) {
                int q = qw + qg * 16 + quad * 4 + r;
                int col = (g * 4 + h) * 64 + dt * 16 + n;
                o_bf[(size_t)(b * SEQ + q) * DMODEL + col] =
                    f2bf(od[qg][dt][r] * linv[r]);
            }
    }
}

extern "C" void kernel_launch(void* const* d_in, const int* in_sizes, int n_in,
                              void* d_out, int out_size, void* d_ws, size_t ws_size,
                              hipStream_t stream) {
    const float* x     = (const float*)d_in[0];
    const float* w_in  = (const float*)d_in[1];
    const float* w_out = (const float*)d_in[2];
    const float* rms_w = (const float*)d_in[3];
    float* out = (float*)d_out;

    // Workspace layout with liveness overlap (peak 76 MB):
    //   [0,48)MB  qkv f32           -> after packs: o_bf [0,16), w_out_bf [16,24)
    //   [48,64)MB y_bf              -> after GEMM-in: Qb
    //   [64,76)MB w_in_bf           -> after GEMM-in: Kb [64,68), Vb [68,72)
    const size_t MB = 1024 * 1024;
    char* ws = (char*)d_ws;
    float*  qkv      = (float*)ws;
    ushort* y_bf     = (ushort*)(ws + 48 * MB);
    ushort* w_in_bf  = (ushort*)(ws + 64 * MB);
    ushort* Qb       = (ushort*)(ws + 48 * MB);
    ushort* Kb       = (ushort*)(ws + 64 * MB);
    ushort* Vb       = (ushort*)(ws + 68 * MB);
    ushort* o_bf     = (ushort*)ws;
    ushort* w_out_bf = (ushort*)(ws + 16 * MB);

    rmsnorm_kernel<<<TOKENS, 256, 0, stream>>>(x, rms_w, y_bf);
    pack_bf16_kernel<<<(CONCAT * DMODEL / 4 + 255) / 256, 256, 0, stream>>>(
        w_in, w_in_bf, CONCAT * DMODEL / 4);

    gemm_nt_8ph<false, 2><<<dim3(CONCAT / 256, TOKENS / 256), 512, 0, stream>>>(
        y_bf, w_in_bf, qkv, nullptr, nullptr, TOKENS, CONCAT, DMODEL);

    pack_qkv_kernel<<<TOKENS + 512, 256, 0, stream>>>(
        qkv, Qb, Kb, Vb);
    pack_bf16_kernel<<<(DMODEL * DMODEL / 4 + 255) / 256, 256, 0, stream>>>(
        w_out, w_out_bf, DMODEL * DMODEL / 4);

    attn_mfma_kernel<<<1024, 256, 0, stream>>>(Qb, Kb, Vb, o_bf);

    gemm_nt_8ph<true, 1><<<dim3(DMODEL / 128, TOKENS / 256), 512, 0, stream>>>(
        o_bf, w_out_bf, nullptr, x, out, TOKENS, DMODEL, DMODEL);
}

// Round 5
// 290.537 us; speedup vs baseline: 1.0940x; 1.0356x over previous
//
#include <hip/hip_runtime.h>
#include <hip/hip_bf16.h>

// fp32 problem: b=2, s=2048, D=2048, 32 q-heads / 8 kv-groups, d=64
#define TOKENS   4096
#define SEQ      2048
#define DMODEL   2048
#define CONCAT   3072
#define NHEADS   32
#define NGROUPS  8
#define HPERG    4
#define CQ       2048
#define CK       512

typedef __attribute__((ext_vector_type(8))) short bf16x8;
typedef __attribute__((ext_vector_type(4))) float f32x4;

__device__ __forceinline__ ushort f2bf(float f) {
    __hip_bfloat16 h = __float2bfloat16(f);
    return __builtin_bit_cast(ushort, h);
}

// packed f32x2 -> bf16x2 (RNE), dst = bf16(hi)<<16 | bf16(lo)
__device__ __forceinline__ uint cvt_pk_bf16(float lo, float hi) {
    uint r;
    asm("v_cvt_pk_bf16_f32 %0, %1, %2" : "=v"(r) : "v"(lo), "v"(hi));
    return r;
}

#define GLOBAL_TO_LDS16(g, l)                                                  \
    __builtin_amdgcn_global_load_lds(                                          \
        (const __attribute__((address_space(1))) void*)(g),                    \
        (__attribute__((address_space(3))) void*)(l), 16, 0, 0)

// ---------------- RMSNorm: one block (256 thr) per token, bf16 out -------
__global__ void rmsnorm_kernel(const float* __restrict__ x,
                               const float* __restrict__ w,
                               ushort* __restrict__ y_bf) {
    int t = blockIdx.x;
    const float4* xr = (const float4*)(x + (size_t)t * DMODEL);
    float4 v[2];
    float ss = 0.f;
#pragma unroll
    for (int i = 0; i < 2; i++) {
        v[i] = xr[threadIdx.x + i * 256];
        ss += v[i].x * v[i].x + v[i].y * v[i].y + v[i].z * v[i].z + v[i].w * v[i].w;
    }
#pragma unroll
    for (int off = 32; off >= 1; off >>= 1) ss += __shfl_xor(ss, off);
    __shared__ float red[4];
    int wid = threadIdx.x >> 6;
    if ((threadIdx.x & 63) == 0) red[wid] = ss;
    __syncthreads();
    float total = red[0] + red[1] + red[2] + red[3];
    float scale = rsqrtf(total * (1.0f / DMODEL) + 1e-6f);
    const float4* wr = (const float4*)w;
    ushort4* yr = (ushort4*)(y_bf + (size_t)t * DMODEL);
#pragma unroll
    for (int i = 0; i < 2; i++) {
        int c = threadIdx.x + i * 256;
        float4 wv = wr[c];
        ushort4 o;
        o.x = f2bf(v[i].x * scale * wv.x);
        o.y = f2bf(v[i].y * scale * wv.y);
        o.z = f2bf(v[i].z * scale * wv.z);
        o.w = f2bf(v[i].w * scale * wv.w);
        yr[c] = o;
    }
}

// ---------------- fp32 -> bf16 cast (weights) ----------------------------
__global__ void pack_bf16_kernel(const float* __restrict__ src,
                                 ushort* __restrict__ dst, int n4) {
    int i = blockIdx.x * 256 + threadIdx.x;
    if (i < n4) {
        float4 v = ((const float4*)src)[i];
        ushort4 o;
        o.x = f2bf(v.x); o.y = f2bf(v.y); o.z = f2bf(v.z); o.w = f2bf(v.w);
        ((ushort4*)dst)[i] = o;
    }
}

// ---------------- 256xBN 8-phase MFMA GEMM -------------------------------
// C[M,N] = A[M,K] * B[N,K]^T, bf16 in / f32 out.  BN = 128*NFRAG.
// 512 thr = 8 waves (2M x 4N); wave tile 128 x (32*NFRAG); BK=64.
// Rolling half-tile buffer, counted vmcnt (6 / 4), raw s_barrier.
// LDS swizzle: linear dest + pre-swizzled global src.
// T1: XCD-aware block swizzle (nwg%8==0 for both call sites -> bijective).
#define LGKM(nn) asm volatile("s_waitcnt lgkmcnt(" #nn ")" ::: "memory")
#define VMC(nn)  asm volatile("s_waitcnt vmcnt(" #nn ")" ::: "memory")
#define SBAR()   __builtin_amdgcn_s_barrier()
#define SCHED0() __builtin_amdgcn_sched_barrier(0)
#define PRIO(p)  __builtin_amdgcn_s_setprio(p)

#define RD_A(mh)                                                              \
    _Pragma("unroll") for (int mi = 0; mi < 4; mi++)                          \
    _Pragma("unroll") for (int ks = 0; ks < 2; ks++)                          \
        af[mi][ks] = *(const bf16x8*)(Ab +                                    \
            ((arow0 + (mh) * 64 + mi * 16) * 8 +                              \
             ((ks * 4 + quad) ^ an)) * 8);

#define RD_B(nh)                                                              \
    _Pragma("unroll") for (int ni = 0; ni < NFRAG; ni++)                      \
    _Pragma("unroll") for (int ks = 0; ks < 2; ks++)                          \
        bfr[nh][ni][ks] = *(const bf16x8*)(Bb +                               \
            ((brow0 + (nh) * (16 * NFRAG) + ni * 16) * 8 +                    \
             ((ks * 4 + quad) ^ an)) * 8);

#define MMQ(mh, nh)                                                           \
    _Pragma("unroll") for (int mi = 0; mi < 4; mi++)                          \
    _Pragma("unroll") for (int ni = 0; ni < NFRAG; ni++)                      \
    _Pragma("unroll") for (int ks = 0; ks < 2; ks++)                          \
        acc[(mh) * 4 + mi][(nh) * NFRAG + ni] =                               \
            __builtin_amdgcn_mfma_f32_16x16x32_bf16(af[mi][ks],               \
                bfr[nh][ni][ks], acc[(mh) * 4 + mi][(nh) * NFRAG + ni],       \
                0, 0, 0);

#define ISSUE_HALF(H_)                                                        \
    {                                                                         \
        int H = (H_);                                                         \
        if (H < 4 * NT) {                                                     \
            int t2 = H >> 2, j2 = H & 3;                                      \
            int k0 = t2 << 6;                                                 \
            if (j2 == 0 || j2 == 3) {                                         \
                int half = (j2 == 3);                                         \
                ushort* lb = (ushort*)&As[t2 & 1][0];                         \
                _Pragma("unroll") for (int c = 0; c < 2; c++) {               \
                    int s = w * 2 + c;                                        \
                    int row = (s >> 3) * 128 + half * 64 + (s & 7) * 8;       \
                    const ushort* g = Aptr +                                  \
                        (size_t)(bm + row + l8) * K + k0 + kb8;               \
                    GLOBAL_TO_LDS16(g, lb + row * 64);                        \
                }                                                             \
            } else {                                                          \
                int half = (j2 == 2);                                         \
                ushort* lb = (ushort*)&Bs[t2 & 1][0];                         \
                if constexpr (NFRAG == 2) {                                   \
                    _Pragma("unroll") for (int c = 0; c < 2; c++) {           \
                        int s = w * 2 + c;                                    \
                        int row = (s >> 2) * 64 + half * 32 + (s & 3) * 8;    \
                        const ushort* g = Bptr +                              \
                            (size_t)(bn + row + l8) * K + k0 + kb8;           \
                        GLOBAL_TO_LDS16(g, lb + row * 64);                    \
                    }                                                         \
                } else {                                                      \
                    int row = (w >> 1) * 32 + half * 16 + (w & 1) * 8;        \
                    const ushort* g = Bptr +                                  \
                        (size_t)(bn + row + l8) * K + k0 + kb8;               \
                    GLOBAL_TO_LDS16(g, lb + row * 64);                        \
                }                                                             \
            }                                                                 \
        }                                                                     \
    }

#define VMC_STEADY()                                                          \
    { if constexpr (NFRAG == 2) { VMC(6); } else { VMC(4); } }

#define TILE(t_, BUF)                                                         \
    {                                                                         \
        const ushort* Ab = &As[BUF][0];                                       \
        const ushort* Bb = &Bs[BUF][0];                                       \
        /* phase 1: A0,B0 -> Q(0,0) */                                        \
        RD_A(0); RD_B(0);                                                     \
        ISSUE_HALF(4 * (t_) + 7);                                             \
        LGKM(8);                                                              \
        SBAR(); LGKM(0); SCHED0();                                            \
        PRIO(1); MMQ(0, 0); PRIO(0);                                          \
        SBAR();                                                               \
        /* phase 2: B1 -> Q(0,1) */                                           \
        RD_B(1);                                                              \
        ISSUE_HALF(4 * (t_) + 8);                                             \
        SBAR(); LGKM(0); SCHED0();                                            \
        PRIO(1); MMQ(0, 1); PRIO(0);                                          \
        SBAR();                                                               \
        /* phase 3: A1 -> Q(1,0) */                                           \
        RD_A(1);                                                              \
        ISSUE_HALF(4 * (t_) + 9);                                             \
        SBAR(); LGKM(0); SCHED0();                                            \
        PRIO(1); MMQ(1, 0); PRIO(0);                                          \
        SBAR();                                                               \
        /* phase 4: Q(1,1) + tile-boundary counted vmcnt */                   \
        ISSUE_HALF(4 * (t_) + 10);                                            \
        SBAR(); SCHED0();                                                     \
        PRIO(1); MMQ(1, 1); PRIO(0);                                          \
        if ((t_) + 2 < NT)        { VMC_STEADY(); }                           \
        else if ((t_) + 2 == NT)  { VMC(0); }                                 \
        SBAR();                                                               \
    }

template <bool EPILOGUE, int NFRAG>
__global__ __launch_bounds__(512, 2) void gemm_nt_8ph(
        const ushort* __restrict__ Aptr, const ushort* __restrict__ Bptr,
        float* __restrict__ C, const float* __restrict__ X,
        float* __restrict__ OUT, int M, int N, int K) {
    __shared__ __align__(16) ushort As[2][256 * 64];
    __shared__ __align__(16) ushort Bs[2][NFRAG * 128 * 64];

    // XCD-aware swizzle: XCD k owns a contiguous chunk of tile space.
    int nwg = (int)(gridDim.x * gridDim.y);
    int lin = (int)(blockIdx.y * gridDim.x + blockIdx.x);
    int swz = lin;
    if ((nwg & 7) == 0) swz = (lin & 7) * (nwg >> 3) + (lin >> 3);
    const int bm = (swz / (int)gridDim.x) * 256;
    const int bn = (swz % (int)gridDim.x) * (128 * NFRAG);

    const int w = threadIdx.x >> 6, lane = threadIdx.x & 63;
    const int n = lane & 15, quad = lane >> 4;
    const int wm = w >> 2, wn = w & 3;
    const int an = n & 7;
    const int l8 = lane >> 3;
    const int kb8 = ((lane & 7) ^ l8) * 8;
    const int arow0 = wm * 128 + n;
    const int brow0 = wn * (32 * NFRAG) + n;
    const int NT = K >> 6;

    f32x4 acc[8][2 * NFRAG] = {};
    bf16x8 af[4][2], bfr[2][NFRAG][2];

    // prologue: pre-issue 7 halves (queue order), land first 4, barrier
    ISSUE_HALF(0); ISSUE_HALF(1); ISSUE_HALF(2); ISSUE_HALF(3);
    ISSUE_HALF(4); ISSUE_HALF(5); ISSUE_HALF(6);
    VMC_STEADY();
    SBAR();

    for (int tt = 0; tt < NT; tt += 2) {
        TILE(tt, 0);
        TILE(tt + 1, 1);
    }

#pragma unroll
    for (int mi = 0; mi < 8; mi++)
#pragma unroll
        for (int ni = 0; ni < 2 * NFRAG; ni++) {
            int row = bm + wm * 128 + mi * 16 + quad * 4;
            int col = bn + wn * (32 * NFRAG) + ni * 16 + n;
#pragma unroll
            for (int r = 0; r < 4; r++) {
                size_t idx = (size_t)(row + r) * N + col;
                float v = acc[mi][ni][r];
                if (EPILOGUE) OUT[idx] = X[idx] + v;
                else          C[idx]   = v;
            }
        }
}

// ------------- pack_qkv: fused RoPE-pack (Q,K) + V transpose -------------
// Blocks [0,TOKENS): RoPE via per-block LDS trig table (32 distinct pairs),
//   pair-processing (d, d+32).  Q pre-scaled by 0.125*log2(e).
// Blocks [TOKENS, TOKENS+512): V transpose to [b][g][d][s] bf16 via LDS.
__global__ void pack_qkv_kernel(const float* __restrict__ qkv,
                                ushort* __restrict__ Qb,
                                ushort* __restrict__ Kb,
                                ushort* __restrict__ Vb) {
    __shared__ float cs[32], sn[32];
    __shared__ float tile[64][65];
    int tid = threadIdx.x;

    if (blockIdx.x < TOKENS) {
        int t = blockIdx.x;
        int b = t >> 11, s = t & (SEQ - 1);
        const float* row = qkv + (size_t)t * CONCAT;
        if (tid < 32) {
            const float LOG2_THETA = 13.287712379549449f;
            float inv = exp2f(-((float)tid / 32.0f) * LOG2_THETA);
            float ang = (float)s * inv;
            cs[tid] = cosf(ang);
            sn[tid] = sinf(ang);
        }
        __syncthreads();
        const float QSCALE = 0.18033688011112042f;  // 0.125 * log2(e)
#pragma unroll
        for (int it = 0; it < (CQ + CK) / 2 / 256; it++) {
            int p = tid + it * 256;
            int head = p >> 5, j = p & 31;
            const float* hb = row + head * 64;
            float x1 = hb[j], x2 = hb[j + 32];
            float c = cs[j], s2 = sn[j];
            float o1 = x1 * c - x2 * s2;
            float o2 = x2 * c + x1 * s2;
            if (head < 32) {
                o1 *= QSCALE; o2 *= QSCALE;
                int g = head >> 2, h = head & 3;
                ushort* q = Qb + ((size_t)((b * 8 + g) * 4 + h) * SEQ + s) * 64;
                q[j]      = f2bf(o1);
                q[j + 32] = f2bf(o2);
            } else {
                int kh = head - 32;
                ushort* kk = Kb + ((size_t)(b * 8 + kh) * SEQ + s) * 64;
                kk[j]      = f2bf(o1);
                kk[j + 32] = f2bf(o2);
            }
        }
    } else {
        int bid = blockIdx.x - TOKENS;
        int st = bid & 31, bg = bid >> 5;
        int b = bg >> 3, g = bg & 7;
        int ls = tid >> 6;
        int d = tid & 63;
#pragma unroll
        for (int i = 0; i < 16; i++) {
            int s = st * 64 + i * 4 + ls;
            tile[i * 4 + ls][d] =
                qkv[(size_t)(b * SEQ + s) * CONCAT + CQ + CK + g * 64 + d];
        }
        __syncthreads();
#pragma unroll
        for (int i = 0; i < 16; i++) {
            int drow = i * 4 + ls;
            int scol = tid & 63;
            Vb[((size_t)(bg * 64 + drow)) * SEQ + st * 64 + scol] =
                f2bf(tile[scol][drow]);
        }
    }
}

// ---------------- MFMA flash attention, v4 -------------------------------
// Block = (b,g,h, 128-query tile); 8 waves x 16 query rows each.
// v4 vs v3: wave count doubled at SAME LDS (Pl scales with q-rows, not
// waves) -> 24 waves/CU occupancy cap (was 12); T5 setprio around MFMA;
// P pack via v_cvt_pk_bf16_f32 (1 op replaces 2 sw-RNE casts + shift/or).
// No-max exp2 softmax (Q pre-scaled): p = v_exp(S2), l = ones-column MFMA.
// S^T via operand swap -> consecutive keys in-lane -> packed-dword P writes.
// K/V staged by direct global_load_lds, double-buffered, counted vmcnt(2)
// (1 K-load + 1 V-load per lane per tile).  Conflict-free reads via XOR on
// the GLOBAL source (both-sides-or-neither):
//   K slot q (16B units) holds (key=q>>3, dblk=(q&7)^(key&7))
//     -> read group (key,dblk) at slot key*8 + (dblk^(key&7))
//   V slot q holds (d=q>>3, kb=(q&7)^(d&7))
//     -> read group (kb,d)   at slot d*8 + (kb^(d&7))
// P per-wave LDS: dwords ((key>>3)*17 + q)*4 + ((key&7)>>1), q in [0,16).
#define AISSUE(kt_, buf_)                                                     \
    {                                                                         \
        const ushort* Kg_ = Kg0 + (kt_) * 64 * 64;                            \
        const ushort* Vg_ = Vg0 + (kt_) * 64;                                 \
        GLOBAL_TO_LDS16(Kg_ + (w * 8 + l3) * 64 + lx * 8,                     \
                        &Kl[buf_][(size_t)threadIdx.x * 8]);                  \
        GLOBAL_TO_LDS16(Vg_ + (size_t)(w * 8 + l3) * SEQ + lx * 8,            \
                        &Vl[buf_][(size_t)threadIdx.x * 8]);                  \
    }

__global__ __launch_bounds__(512) void attn_mfma_kernel(
        const ushort* __restrict__ Qb, const ushort* __restrict__ Kb,
        const ushort* __restrict__ Vb, ushort* __restrict__ o_bf) {
    __shared__ __align__(16) ushort Kl[2][512 * 8];
    __shared__ __align__(16) ushort Vl[2][512 * 8];
    __shared__ __align__(16) uint   Pl[8][544];

    int blk = blockIdx.x;
    int qt  = 15 - (blk >> 6);          // longest blocks dispatch first
    int bgh = blk & 63;
    int h = bgh & 3, g = (bgh >> 2) & 7, b = bgh >> 5;
    int w = threadIdx.x >> 6, lane = threadIdx.x & 63;
    int n = lane & 15, quad = lane >> 4;
    const int an = n & 7;
    int Q0 = qt * 128;
    int qw = Q0 + w * 16;               // wave's first query row

    // staging lane constants
    const int l3 = lane >> 3;
    const int lx = (lane & 7) ^ l3;

    const ushort* Qh  = Qb + (size_t)((b * 8 + g) * 4 + h) * (SEQ * 64);
    const ushort* Kg0 = Kb + (size_t)(b * 8 + g) * (SEQ * 64);
    const ushort* Vg0 = Vb + (size_t)(b * 8 + g) * (64 * SEQ);

    // Q fragments (rows of Q; per-lane data for B-operand use)
    bf16x8 aq[2];
#pragma unroll
    for (int ks = 0; ks < 2; ks++)
        aq[ks] = *(const bf16x8*)(
            Qh + (size_t)(qw + n) * 64 + ks * 32 + quad * 8);

    f32x4 od[4] = {};
    f32x4 od4 = {};

    short onev = (n == 0) ? (short)0x3F80 : (short)0;
    bf16x8 bones = {onev, onev, onev, onev, onev, onev, onev, onev};

    uint* Pw = Pl[w];
    int nkt = qt * 2 + 2;

    // prologue: tiles 0 and 1 in flight (2 loads each per lane)
    AISSUE(0, 0);
    AISSUE(1, 1);

    for (int kt = 0; kt < nkt; kt++) {
        int buf = kt & 1;
        if (kt + 1 < nkt) { VMC(2); } else { VMC(0); }
        SBAR(); SCHED0();                // buf[kt&1] fully loaded, all waves

        bool act = (kt * 64 <= qw + 15);   // do this wave's rows see kt?
        if (act) {
            const ushort* Kb_ = Kl[buf];
            const ushort* Vb_ = Vl[buf];

            // S^T = K Q^T (operand swap), exp2, cvt_pk, P write
#pragma unroll
            for (int t16k = 0; t16k < 4; t16k++) {
                int krow = (t16k * 16 + n) * 8;
                bf16x8 kf0 = *(const bf16x8*)(Kb_ + (krow + (quad ^ an)) * 8);
                bf16x8 kf1 = *(const bf16x8*)(Kb_ + (krow + ((quad + 4) ^ an)) * 8);
                int key0 = kt * 64 + t16k * 16 + quad * 4;
                f32x4 c = {};
                PRIO(1);
                c = __builtin_amdgcn_mfma_f32_16x16x32_bf16(kf0, aq[0], c, 0, 0, 0);
                c = __builtin_amdgcn_mfma_f32_16x16x32_bf16(kf1, aq[1], c, 0, 0, 0);
                PRIO(0);
                int qrow = qw + n;
                float p[4];
                if (kt * 64 + 63 > qw) {             // tile may mask
#pragma unroll
                    for (int r = 0; r < 4; r++)
                        p[r] = (key0 + r <= qrow) ? __builtin_amdgcn_exp2f(c[r]) : 0.f;
                } else {
#pragma unroll
                    for (int r = 0; r < 4; r++)
                        p[r] = __builtin_amdgcn_exp2f(c[r]);
                }
                uint d0 = cvt_pk_bf16(p[0], p[1]);
                uint d1 = cvt_pk_bf16(p[2], p[3]);
                int base = ((t16k * 2 + (quad >> 1)) * 17 + n) * 4
                           + (quad & 1) * 2;
                Pw[base]     = d0;
                Pw[base + 1] = d1;
            }

            // O += P V   (+ ones column accumulates l)
#pragma unroll
            for (int kb2 = 0; kb2 < 2; kb2++) {
                int kb = kb2 * 4 + quad;
                bf16x8 bv[4];
#pragma unroll
                for (int dt = 0; dt < 4; dt++)
                    bv[dt] = *(const bf16x8*)(Vb_ +
                        (((dt * 16 + n) * 8 + (kb ^ an)) * 8));
                bf16x8 ap = *(const bf16x8*)(
                    (const ushort*)Pw + ((kb2 * 4 + quad) * 17 + n) * 8);
                PRIO(1);
#pragma unroll
                for (int dt = 0; dt < 4; dt++)
                    od[dt] = __builtin_amdgcn_mfma_f32_16x16x32_bf16(
                        ap, bv[dt], od[dt], 0, 0, 0);
                od4 = __builtin_amdgcn_mfma_f32_16x16x32_bf16(
                    ap, bones, od4, 0, 0, 0);
                PRIO(0);
            }
        }

        SCHED0(); SBAR();                // all reads of buf done
        if (kt + 2 < nkt) AISSUE(kt + 2, buf);
    }

    // epilogue: l lives in column 0 of od4 (lane n==0); broadcast, divide
    float linv[4];
#pragma unroll
    for (int r = 0; r < 4; r++) {
        float lv = __shfl(od4[r], lane & 48);
        linv[r] = __builtin_amdgcn_rcpf(lv);
    }
#pragma unroll
    for (int dt = 0; dt < 4; dt++)
#pragma unroll
        for (int r = 0; r < 4; r++) {
            int q = qw + quad * 4 + r;
            int col = (g * 4 + h) * 64 + dt * 16 + n;
            o_bf[(size_t)(b * SEQ + q) * DMODEL + col] =
                f2bf(od[dt][r] * linv[r]);
        }
}

extern "C" void kernel_launch(void* const* d_in, const int* in_sizes, int n_in,
                              void* d_out, int out_size, void* d_ws, size_t ws_size,
                              hipStream_t stream) {
    const float* x     = (const float*)d_in[0];
    const float* w_in  = (const float*)d_in[1];
    const float* w_out = (const float*)d_in[2];
    const float* rms_w = (const float*)d_in[3];
    float* out = (float*)d_out;

    // Workspace layout with liveness overlap (peak 76 MB):
    //   [0,48)MB  qkv f32           -> after packs: o_bf [0,16), w_out_bf [16,24)
    //   [48,64)MB y_bf              -> after GEMM-in: Qb
    //   [64,76)MB w_in_bf           -> after GEMM-in: Kb [64,68), Vb [68,72)
    const size_t MB = 1024 * 1024;
    char* ws = (char*)d_ws;
    float*  qkv      = (float*)ws;
    ushort* y_bf     = (ushort*)(ws + 48 * MB);
    ushort* w_in_bf  = (ushort*)(ws + 64 * MB);
    ushort* Qb       = (ushort*)(ws + 48 * MB);
    ushort* Kb       = (ushort*)(ws + 64 * MB);
    ushort* Vb       = (ushort*)(ws + 68 * MB);
    ushort* o_bf     = (ushort*)ws;
    ushort* w_out_bf = (ushort*)(ws + 16 * MB);

    rmsnorm_kernel<<<TOKENS, 256, 0, stream>>>(x, rms_w, y_bf);
    pack_bf16_kernel<<<(CONCAT * DMODEL / 4 + 255) / 256, 256, 0, stream>>>(
        w_in, w_in_bf, CONCAT * DMODEL / 4);

    gemm_nt_8ph<false, 2><<<dim3(CONCAT / 256, TOKENS / 256), 512, 0, stream>>>(
        y_bf, w_in_bf, qkv, nullptr, nullptr, TOKENS, CONCAT, DMODEL);

    pack_qkv_kernel<<<TOKENS + 512, 256, 0, stream>>>(
        qkv, Qb, Kb, Vb);
    pack_bf16_kernel<<<(DMODEL * DMODEL / 4 + 255) / 256, 256, 0, stream>>>(
        w_out, w_out_bf, DMODEL * DMODEL / 4);

    attn_mfma_kernel<<<1024, 512, 0, stream>>>(Qb, Kb, Vb, o_bf);

    gemm_nt_8ph<true, 1><<<dim3(DMODEL / 128, TOKENS / 256), 512, 0, stream>>>(
        o_bf, w_out_bf, nullptr, x, out, TOKENS, DMODEL, DMODEL);
}

// Round 6
// 279.840 us; speedup vs baseline: 1.1358x; 1.0382x over previous
//
#include <hip/hip_runtime.h>
#include <hip/hip_bf16.h>

// fp32 problem: b=2, s=2048, D=2048, 32 q-heads / 8 kv-groups, d=64
#define TOKENS   4096
#define SEQ      2048
#define DMODEL   2048
#define CONCAT   3072
#define NHEADS   32
#define NGROUPS  8
#define HPERG    4
#define CQ       2048
#define CK       512

typedef __attribute__((ext_vector_type(8))) short bf16x8;
typedef __attribute__((ext_vector_type(4))) float f32x4;

__device__ __forceinline__ ushort f2bf(float f) {
    __hip_bfloat16 h = __float2bfloat16(f);
    return __builtin_bit_cast(ushort, h);
}

// packed f32x2 -> bf16x2 (RNE), dst = bf16(hi)<<16 | bf16(lo)
__device__ __forceinline__ uint cvt_pk_bf16(float lo, float hi) {
    uint r;
    asm("v_cvt_pk_bf16_f32 %0, %1, %2" : "=v"(r) : "v"(lo), "v"(hi));
    return r;
}

#define GLOBAL_TO_LDS16(g, l)                                                  \
    __builtin_amdgcn_global_load_lds(                                          \
        (const __attribute__((address_space(1))) void*)(g),                    \
        (__attribute__((address_space(3))) void*)(l), 16, 0, 0)

// ---------------- RMSNorm: one block (256 thr) per token, bf16 out -------
__global__ void rmsnorm_kernel(const float* __restrict__ x,
                               const float* __restrict__ w,
                               ushort* __restrict__ y_bf) {
    int t = blockIdx.x;
    const float4* xr = (const float4*)(x + (size_t)t * DMODEL);
    float4 v[2];
    float ss = 0.f;
#pragma unroll
    for (int i = 0; i < 2; i++) {
        v[i] = xr[threadIdx.x + i * 256];
        ss += v[i].x * v[i].x + v[i].y * v[i].y + v[i].z * v[i].z + v[i].w * v[i].w;
    }
#pragma unroll
    for (int off = 32; off >= 1; off >>= 1) ss += __shfl_xor(ss, off);
    __shared__ float red[4];
    int wid = threadIdx.x >> 6;
    if ((threadIdx.x & 63) == 0) red[wid] = ss;
    __syncthreads();
    float total = red[0] + red[1] + red[2] + red[3];
    float scale = rsqrtf(total * (1.0f / DMODEL) + 1e-6f);
    const float4* wr = (const float4*)w;
    ushort4* yr = (ushort4*)(y_bf + (size_t)t * DMODEL);
#pragma unroll
    for (int i = 0; i < 2; i++) {
        int c = threadIdx.x + i * 256;
        float4 wv = wr[c];
        ushort4 o;
        o.x = f2bf(v[i].x * scale * wv.x);
        o.y = f2bf(v[i].y * scale * wv.y);
        o.z = f2bf(v[i].z * scale * wv.z);
        o.w = f2bf(v[i].w * scale * wv.w);
        yr[c] = o;
    }
}

// ---------------- fp32 -> bf16 cast, both weight matrices ---------------
#define N4_WIN  (CONCAT * DMODEL / 4)
#define N4_WOUT (DMODEL * DMODEL / 4)
__global__ void pack_weights_kernel(const float* __restrict__ w_in,
                                    const float* __restrict__ w_out,
                                    ushort* __restrict__ w_in_bf,
                                    ushort* __restrict__ w_out_bf) {
    int i = blockIdx.x * 256 + threadIdx.x;
    const float* src;
    ushort* dst;
    int j;
    if (i < N4_WIN) { src = w_in; dst = w_in_bf; j = i; }
    else if (i < N4_WIN + N4_WOUT) { src = w_out; dst = w_out_bf; j = i - N4_WIN; }
    else return;
    float4 v = ((const float4*)src)[j];
    ushort4 o;
    o.x = f2bf(v.x); o.y = f2bf(v.y); o.z = f2bf(v.z); o.w = f2bf(v.w);
    ((ushort4*)dst)[j] = o;
}

// ---------------- 256xBN 8-phase MFMA GEMM -------------------------------
// C[M,N] = A[M,K] * B[N,K]^T, bf16 in.  BN = 128*NFRAG.
// 512 thr = 8 waves (2M x 4N); wave tile 128 x (32*NFRAG); BK=64.
// Rolling half-tile buffer, counted vmcnt (6 / 4), raw s_barrier.
// LDS swizzle: linear dest + pre-swizzled global src.
// T1: XCD-aware block swizzle (nwg%8==0 for both call sites -> bijective).
// EPI=1: OUT = X + acc (f32).   EPI=2 (NFRAG=2, gemm-in only): fused
// RoPE+bf16 pack straight from acc into Qb/Kb (and V transpose into Vb) --
// qkv f32 is never materialized.  Wave cols = exactly one 64-wide head;
// RoPE pair partner of acc[mi][ni] is acc[mi][ni+2] (d and d+32), so the
// rotation is lane-local.  cos/sin from a per-block LDS table (256 rows x
// 32 freqs, stride 37 -> <=2-way banks), same float path as the old
// pack_qkv (exp2f/cosf/sinf) -> bit-identical numerics.
#define LGKM(nn) asm volatile("s_waitcnt lgkmcnt(" #nn ")" ::: "memory")
#define VMC(nn)  asm volatile("s_waitcnt vmcnt(" #nn ")" ::: "memory")
#define SBAR()   __builtin_amdgcn_s_barrier()
#define SCHED0() __builtin_amdgcn_sched_barrier(0)
#define PRIO(p)  __builtin_amdgcn_s_setprio(p)

#define RD_A(mh)                                                              \
    _Pragma("unroll") for (int mi = 0; mi < 4; mi++)                          \
    _Pragma("unroll") for (int ks = 0; ks < 2; ks++)                          \
        af[mi][ks] = *(const bf16x8*)(Ab +                                    \
            ((arow0 + (mh) * 64 + mi * 16) * 8 +                              \
             ((ks * 4 + quad) ^ an)) * 8);

#define RD_B(nh)                                                              \
    _Pragma("unroll") for (int ni = 0; ni < NFRAG; ni++)                      \
    _Pragma("unroll") for (int ks = 0; ks < 2; ks++)                          \
        bfr[nh][ni][ks] = *(const bf16x8*)(Bb +                               \
            ((brow0 + (nh) * (16 * NFRAG) + ni * 16) * 8 +                    \
             ((ks * 4 + quad) ^ an)) * 8);

#define MMQ(mh, nh)                                                           \
    _Pragma("unroll") for (int mi = 0; mi < 4; mi++)                          \
    _Pragma("unroll") for (int ni = 0; ni < NFRAG; ni++)                      \
    _Pragma("unroll") for (int ks = 0; ks < 2; ks++)                          \
        acc[(mh) * 4 + mi][(nh) * NFRAG + ni] =                               \
            __builtin_amdgcn_mfma_f32_16x16x32_bf16(af[mi][ks],               \
                bfr[nh][ni][ks], acc[(mh) * 4 + mi][(nh) * NFRAG + ni],       \
                0, 0, 0);

#define ISSUE_HALF(H_)                                                        \
    {                                                                         \
        int H = (H_);                                                         \
        if (H < 4 * NT) {                                                     \
            int t2 = H >> 2, j2 = H & 3;                                      \
            int k0 = t2 << 6;                                                 \
            if (j2 == 0 || j2 == 3) {                                         \
                int half = (j2 == 3);                                         \
                ushort* lb = (ushort*)&As[t2 & 1][0];                         \
                _Pragma("unroll") for (int c = 0; c < 2; c++) {               \
                    int s = w * 2 + c;                                        \
                    int row = (s >> 3) * 128 + half * 64 + (s & 7) * 8;       \
                    const ushort* g = Aptr +                                  \
                        (size_t)(bm + row + l8) * K + k0 + kb8;               \
                    GLOBAL_TO_LDS16(g, lb + row * 64);                        \
                }                                                             \
            } else {                                                          \
                int half = (j2 == 2);                                         \
                ushort* lb = (ushort*)&Bs[t2 & 1][0];                         \
                if constexpr (NFRAG == 2) {                                   \
                    _Pragma("unroll") for (int c = 0; c < 2; c++) {           \
                        int s = w * 2 + c;                                    \
                        int row = (s >> 2) * 64 + half * 32 + (s & 3) * 8;    \
                        const ushort* g = Bptr +                              \
                            (size_t)(bn + row + l8) * K + k0 + kb8;           \
                        GLOBAL_TO_LDS16(g, lb + row * 64);                    \
                    }                                                         \
                } else {                                                      \
                    int row = (w >> 1) * 32 + half * 16 + (w & 1) * 8;        \
                    const ushort* g = Bptr +                                  \
                        (size_t)(bn + row + l8) * K + k0 + kb8;               \
                    GLOBAL_TO_LDS16(g, lb + row * 64);                        \
                }                                                             \
            }                                                                 \
        }                                                                     \
    }

#define VMC_STEADY()                                                          \
    { if constexpr (NFRAG == 2) { VMC(6); } else { VMC(4); } }

#define TILE(t_, BUF)                                                         \
    {                                                                         \
        const ushort* Ab = &As[BUF][0];                                       \
        const ushort* Bb = &Bs[BUF][0];                                       \
        /* phase 1: A0,B0 -> Q(0,0) */                                        \
        RD_A(0); RD_B(0);                                                     \
        ISSUE_HALF(4 * (t_) + 7);                                             \
        LGKM(8);                                                              \
        SBAR(); LGKM(0); SCHED0();                                            \
        PRIO(1); MMQ(0, 0); PRIO(0);                                          \
        SBAR();                                                               \
        /* phase 2: B1 -> Q(0,1) */                                           \
        RD_B(1);                                                              \
        ISSUE_HALF(4 * (t_) + 8);                                             \
        SBAR(); LGKM(0); SCHED0();                                            \
        PRIO(1); MMQ(0, 1); PRIO(0);                                          \
        SBAR();                                                               \
        /* phase 3: A1 -> Q(1,0) */                                           \
        RD_A(1);                                                              \
        ISSUE_HALF(4 * (t_) + 9);                                             \
        SBAR(); LGKM(0); SCHED0();                                            \
        PRIO(1); MMQ(1, 0); PRIO(0);                                          \
        SBAR();                                                               \
        /* phase 4: Q(1,1) + tile-boundary counted vmcnt */                   \
        ISSUE_HALF(4 * (t_) + 10);                                            \
        SBAR(); SCHED0();                                                     \
        PRIO(1); MMQ(1, 1); PRIO(0);                                          \
        if ((t_) + 2 < NT)        { VMC_STEADY(); }                           \
        else if ((t_) + 2 == NT)  { VMC(0); }                                 \
        SBAR();                                                               \
    }

template <int EPI, int NFRAG>
__global__ __launch_bounds__(512, 2) void gemm_nt_8ph(
        const ushort* __restrict__ Aptr, const ushort* __restrict__ Bptr,
        const float* __restrict__ X, float* __restrict__ OUT,
        ushort* __restrict__ Qb_, ushort* __restrict__ Kb_,
        ushort* __restrict__ Vb_, int M, int N, int K) {
    __shared__ __align__(16) ushort As[2][256 * 64];
    __shared__ __align__(16) ushort Bs[2][NFRAG * 128 * 64];

    // XCD-aware swizzle: XCD k owns a contiguous chunk of tile space.
    int nwg = (int)(gridDim.x * gridDim.y);
    int lin = (int)(blockIdx.y * gridDim.x + blockIdx.x);
    int swz = lin;
    if ((nwg & 7) == 0) swz = (lin & 7) * (nwg >> 3) + (lin >> 3);
    const int bm = (swz / (int)gridDim.x) * 256;
    const int bn = (swz % (int)gridDim.x) * (128 * NFRAG);

    const int w = threadIdx.x >> 6, lane = threadIdx.x & 63;
    const int n = lane & 15, quad = lane >> 4;
    const int wm = w >> 2, wn = w & 3;
    const int an = n & 7;
    const int l8 = lane >> 3;
    const int kb8 = ((lane & 7) ^ l8) * 8;
    const int arow0 = wm * 128 + n;
    const int brow0 = wn * (32 * NFRAG) + n;
    const int NT = K >> 6;

    f32x4 acc[8][2 * NFRAG] = {};
    bf16x8 af[4][2], bfr[2][NFRAG][2];

    // prologue: pre-issue 7 halves (queue order), land first 4, barrier
    ISSUE_HALF(0); ISSUE_HALF(1); ISSUE_HALF(2); ISSUE_HALF(3);
    ISSUE_HALF(4); ISSUE_HALF(5); ISSUE_HALF(6);
    VMC_STEADY();
    SBAR();

    for (int tt = 0; tt < NT; tt += 2) {
        TILE(tt, 0);
        TILE(tt + 1, 1);
    }

    if constexpr (EPI == 2) {
        // ---- fused RoPE + pack epilogue (NFRAG==2 only) ----
        float* cosT = (float*)&As[0][0];   // 256 x 32, stride 37 f32
        float* sinT = (float*)&Bs[0][0];
        const float LOG2_THETA = 13.287712379549449f;
        const int bq = bm >> 11;           // batch (BM=256 divides 2048)
        const int s0 = bm & 2047;          // first seq pos of this block
#pragma unroll
        for (int t = 0; t < 16; t++) {
            int e = (int)threadIdx.x + t * 512;
            int sl = e >> 5, j = e & 31;
            float inv = exp2f(-((float)j / 32.0f) * LOG2_THETA);
            float ang = (float)(s0 + sl) * inv;
            cosT[sl * 37 + j] = cosf(ang);
            sinT[sl * 37 + j] = sinf(ang);
        }
        __syncthreads();

        int col0 = bn + wn * 64;           // wave's head base (one full head)
        int slb = wm * 128 + quad * 4;
        if (col0 < CQ + CK) {
            bool isQ = col0 < CQ;
            ushort* base;
            if (isQ) {
                int head = col0 >> 6;
                int gq = head >> 2, hq = head & 3;
                base = Qb_ + ((size_t)((bq * 8 + gq) * 4 + hq) * SEQ) * 64;
            } else {
                int kh = (col0 - CQ) >> 6;
                base = Kb_ + ((size_t)(bq * 8 + kh) * SEQ) * 64;
            }
            const float QS = 0.18033688011112042f;   // 0.125 * log2(e)
#pragma unroll
            for (int mi = 0; mi < 8; mi++)
#pragma unroll
                for (int r = 0; r < 4; r++) {
                    int sl = slb + mi * 16 + r;
                    int s = s0 + sl;
#pragma unroll
                    for (int jj = 0; jj < 2; jj++) {
                        int j = jj * 16 + n;
                        float c  = cosT[sl * 37 + j];
                        float sv = sinT[sl * 37 + j];
                        float x1 = acc[mi][jj][r];
                        float x2 = acc[mi][jj + 2][r];
                        float o1 = x1 * c - x2 * sv;
                        float o2 = x2 * c + x1 * sv;
                        if (isQ) { o1 *= QS; o2 *= QS; }
                        base[(size_t)s * 64 + j]      = f2bf(o1);
                        base[(size_t)s * 64 + j + 32] = f2bf(o2);
                    }
                }
        } else {
            int vh = (col0 - CQ - CK) >> 6;
            ushort* base = Vb_ + (size_t)(bq * 8 + vh) * 64 * SEQ;
#pragma unroll
            for (int mi = 0; mi < 8; mi++)
#pragma unroll
                for (int ni = 0; ni < 2 * NFRAG; ni++) {
                    int d = ni * 16 + n;
#pragma unroll
                    for (int r = 0; r < 4; r++) {
                        int s = s0 + slb + mi * 16 + r;
                        base[(size_t)d * SEQ + s] = f2bf(acc[mi][ni][r]);
                    }
                }
        }
    } else {
#pragma unroll
        for (int mi = 0; mi < 8; mi++)
#pragma unroll
            for (int ni = 0; ni < 2 * NFRAG; ni++) {
                int row = bm + wm * 128 + mi * 16 + quad * 4;
                int col = bn + wn * (32 * NFRAG) + ni * 16 + n;
#pragma unroll
                for (int r = 0; r < 4; r++) {
                    size_t idx = (size_t)(row + r) * N + col;
                    OUT[idx] = X[idx] + acc[mi][ni][r];
                }
            }
    }
}

// ---------------- MFMA flash attention, v4 -------------------------------
// Block = (b,g,h, 128-query tile); 8 waves x 16 query rows each.
// No-max exp2 softmax (Q pre-scaled): p = v_exp(S2), l = ones-column MFMA.
// S^T via operand swap -> consecutive keys in-lane -> packed-dword P writes.
// K/V staged by direct global_load_lds, double-buffered, counted vmcnt(2).
// Conflict-free reads via XOR on the GLOBAL source (both-sides-or-neither).
// P per-wave LDS: dwords ((key>>3)*17 + q)*4 + ((key&7)>>1), q in [0,16).
#define AISSUE(kt_, buf_)                                                     \
    {                                                                         \
        const ushort* Kg_ = Kg0 + (kt_) * 64 * 64;                            \
        const ushort* Vg_ = Vg0 + (kt_) * 64;                                 \
        GLOBAL_TO_LDS16(Kg_ + (w * 8 + l3) * 64 + lx * 8,                     \
                        &Kl[buf_][(size_t)threadIdx.x * 8]);                  \
        GLOBAL_TO_LDS16(Vg_ + (size_t)(w * 8 + l3) * SEQ + lx * 8,            \
                        &Vl[buf_][(size_t)threadIdx.x * 8]);                  \
    }

__global__ __launch_bounds__(512) void attn_mfma_kernel(
        const ushort* __restrict__ Qb, const ushort* __restrict__ Kb,
        const ushort* __restrict__ Vb, ushort* __restrict__ o_bf) {
    __shared__ __align__(16) ushort Kl[2][512 * 8];
    __shared__ __align__(16) ushort Vl[2][512 * 8];
    __shared__ __align__(16) uint   Pl[8][544];

    int blk = blockIdx.x;
    int qt  = 15 - (blk >> 6);          // longest blocks dispatch first
    int bgh = blk & 63;
    int h = bgh & 3, g = (bgh >> 2) & 7, b = bgh >> 5;
    int w = threadIdx.x >> 6, lane = threadIdx.x & 63;
    int n = lane & 15, quad = lane >> 4;
    const int an = n & 7;
    int Q0 = qt * 128;
    int qw = Q0 + w * 16;               // wave's first query row

    // staging lane constants
    const int l3 = lane >> 3;
    const int lx = (lane & 7) ^ l3;

    const ushort* Qh  = Qb + (size_t)((b * 8 + g) * 4 + h) * (SEQ * 64);
    const ushort* Kg0 = Kb + (size_t)(b * 8 + g) * (SEQ * 64);
    const ushort* Vg0 = Vb + (size_t)(b * 8 + g) * (64 * SEQ);

    // Q fragments (rows of Q; per-lane data for B-operand use)
    bf16x8 aq[2];
#pragma unroll
    for (int ks = 0; ks < 2; ks++)
        aq[ks] = *(const bf16x8*)(
            Qh + (size_t)(qw + n) * 64 + ks * 32 + quad * 8);

    f32x4 od[4] = {};
    f32x4 od4 = {};

    short onev = (n == 0) ? (short)0x3F80 : (short)0;
    bf16x8 bones = {onev, onev, onev, onev, onev, onev, onev, onev};

    uint* Pw = Pl[w];
    int nkt = qt * 2 + 2;

    // prologue: tiles 0 and 1 in flight (2 loads each per lane)
    AISSUE(0, 0);
    AISSUE(1, 1);

    for (int kt = 0; kt < nkt; kt++) {
        int buf = kt & 1;
        if (kt + 1 < nkt) { VMC(2); } else { VMC(0); }
        SBAR(); SCHED0();                // buf[kt&1] fully loaded, all waves

        bool act = (kt * 64 <= qw + 15);   // do this wave's rows see kt?
        if (act) {
            const ushort* Kb_ = Kl[buf];
            const ushort* Vb_ = Vl[buf];

            // S^T = K Q^T (operand swap), exp2, cvt_pk, P write
#pragma unroll
            for (int t16k = 0; t16k < 4; t16k++) {
                int krow = (t16k * 16 + n) * 8;
                bf16x8 kf0 = *(const bf16x8*)(Kb_ + (krow + (quad ^ an)) * 8);
                bf16x8 kf1 = *(const bf16x8*)(Kb_ + (krow + ((quad + 4) ^ an)) * 8);
                int key0 = kt * 64 + t16k * 16 + quad * 4;
                f32x4 c = {};
                PRIO(1);
                c = __builtin_amdgcn_mfma_f32_16x16x32_bf16(kf0, aq[0], c, 0, 0, 0);
                c = __builtin_amdgcn_mfma_f32_16x16x32_bf16(kf1, aq[1], c, 0, 0, 0);
                PRIO(0);
                int qrow = qw + n;
                float p[4];
                if (kt * 64 + 63 > qw) {             // tile may mask
#pragma unroll
                    for (int r = 0; r < 4; r++)
                        p[r] = (key0 + r <= qrow) ? __builtin_amdgcn_exp2f(c[r]) : 0.f;
                } else {
#pragma unroll
                    for (int r = 0; r < 4; r++)
                        p[r] = __builtin_amdgcn_exp2f(c[r]);
                }
                uint d0 = cvt_pk_bf16(p[0], p[1]);
                uint d1 = cvt_pk_bf16(p[2], p[3]);
                int base = ((t16k * 2 + (quad >> 1)) * 17 + n) * 4
                           + (quad & 1) * 2;
                Pw[base]     = d0;
                Pw[base + 1] = d1;
            }

            // O += P V   (+ ones column accumulates l)
#pragma unroll
            for (int kb2 = 0; kb2 < 2; kb2++) {
                int kb = kb2 * 4 + quad;
                bf16x8 bv[4];
#pragma unroll
                for (int dt = 0; dt < 4; dt++)
                    bv[dt] = *(const bf16x8*)(Vb_ +
                        (((dt * 16 + n) * 8 + (kb ^ an)) * 8));
                bf16x8 ap = *(const bf16x8*)(
                    (const ushort*)Pw + ((kb2 * 4 + quad) * 17 + n) * 8);
                PRIO(1);
#pragma unroll
                for (int dt = 0; dt < 4; dt++)
                    od[dt] = __builtin_amdgcn_mfma_f32_16x16x32_bf16(
                        ap, bv[dt], od[dt], 0, 0, 0);
                od4 = __builtin_amdgcn_mfma_f32_16x16x32_bf16(
                    ap, bones, od4, 0, 0, 0);
                PRIO(0);
            }
        }

        SCHED0(); SBAR();                // all reads of buf done
        if (kt + 2 < nkt) AISSUE(kt + 2, buf);
    }

    // epilogue: l lives in column 0 of od4 (lane n==0); broadcast, divide
    float linv[4];
#pragma unroll
    for (int r = 0; r < 4; r++) {
        float lv = __shfl(od4[r], lane & 48);
        linv[r] = __builtin_amdgcn_rcpf(lv);
    }
#pragma unroll
    for (int dt = 0; dt < 4; dt++)
#pragma unroll
        for (int r = 0; r < 4; r++) {
            int q = qw + quad * 4 + r;
            int col = (g * 4 + h) * 64 + dt * 16 + n;
            o_bf[(size_t)(b * SEQ + q) * DMODEL + col] =
                f2bf(od[dt][r] * linv[r]);
        }
}

extern "C" void kernel_launch(void* const* d_in, const int* in_sizes, int n_in,
                              void* d_out, int out_size, void* d_ws, size_t ws_size,
                              hipStream_t stream) {
    const float* x     = (const float*)d_in[0];
    const float* w_in  = (const float*)d_in[1];
    const float* w_out = (const float*)d_in[2];
    const float* rms_w = (const float*)d_in[3];
    float* out = (float*)d_out;

    // Workspace layout (all ranges disjoint; no liveness aliasing needed):
    //   [0,16)   Qb bf16      [16,20) Kb     [20,24) Vb
    //   [24,40)  o_bf bf16    [40,48) w_out_bf
    //   [48,64)  y_bf bf16    [64,76) w_in_bf
    const size_t MB = 1024 * 1024;
    char* ws = (char*)d_ws;
    ushort* Qb       = (ushort*)ws;
    ushort* Kb       = (ushort*)(ws + 16 * MB);
    ushort* Vb       = (ushort*)(ws + 20 * MB);
    ushort* o_bf     = (ushort*)(ws + 24 * MB);
    ushort* w_out_bf = (ushort*)(ws + 40 * MB);
    ushort* y_bf     = (ushort*)(ws + 48 * MB);
    ushort* w_in_bf  = (ushort*)(ws + 64 * MB);

    rmsnorm_kernel<<<TOKENS, 256, 0, stream>>>(x, rms_w, y_bf);
    pack_weights_kernel<<<(N4_WIN + N4_WOUT + 255) / 256, 256, 0, stream>>>(
        w_in, w_out, w_in_bf, w_out_bf);

    // GEMM-in with fused RoPE/pack epilogue: writes Qb/Kb/Vb directly.
    gemm_nt_8ph<2, 2><<<dim3(CONCAT / 256, TOKENS / 256), 512, 0, stream>>>(
        y_bf, w_in_bf, nullptr, nullptr, Qb, Kb, Vb, TOKENS, CONCAT, DMODEL);

    attn_mfma_kernel<<<1024, 512, 0, stream>>>(Qb, Kb, Vb, o_bf);

    gemm_nt_8ph<1, 1><<<dim3(DMODEL / 128, TOKENS / 256), 512, 0, stream>>>(
        o_bf, w_out_bf, x, out, nullptr, nullptr, nullptr,
        TOKENS, DMODEL, DMODEL);
}